// Round 3
// baseline (928.110 us; speedup 1.0000x reference)
//
#include <hip/hip_runtime.h>
#include <math.h>

#define EPSF 1e-7f
#define Bsz 2
#define Cch 1024
#define Hh 60
#define Ssz 3600
#define HID 256
#define TDIM 300
#define MH 473

// pool tiling
#define TROWS 15
#define LROWS 21          // TROWS + 6 halo
#define LPITCH 68         // 4-col zero pad both sides of 60 cols
#define CPG 8             // channels per block (processed as 4 float2 pairs)

// workspace layout (float offsets)
// [0, 43216) zeroed by hipMemsetAsync each launch (SN2 + DOT planes + barrier cnt)
#define OFF_SN2    0               // 6*3600 sum over channels of pool^2 (atomic)
#define OFF_DOT    21600           // 6*3600 dot planes (atomic)
#define OFF_CNT    43200           // 16 (barrier counter in [0])
#define OFF_WMAP   43216           // 6*3600  mask-premultiplied pool(1/sn)
#define OFF_V      64816           // 6*1024
#define OFF_NORM   70960           // 6*3600 normalized sim planes
#define OFF_SCORE  92560           // 2*3600
#define OFF_KBAR   99760           // 2*256
#define OFF_U      100272          // 2*256

#define NBLK 512

// software grid barrier: monotonic counter, release-add + acquire-spin.
// co-residency guaranteed: launch_bounds(256,2) -> VGPR<=256 -> 2 blocks/CU
// capacity (LDS 39984*2 <= 160K), grid = 512 = 2*256CU.
__device__ __forceinline__ void gbar(int* cnt, int round) {
    __syncthreads();
    if (threadIdx.x == 0) {
        __hip_atomic_fetch_add(cnt, 1, __ATOMIC_RELEASE, __HIP_MEMORY_SCOPE_AGENT);
        while (__hip_atomic_load(cnt, __ATOMIC_ACQUIRE, __HIP_MEMORY_SCOPE_AGENT)
               < NBLK * round)
            __builtin_amdgcn_s_sleep(1);
    }
    __syncthreads();
}

__global__ void __launch_bounds__(256, 2)
k_mega(const float* __restrict__ weight, const float* __restrict__ query,
       const float* __restrict__ supp,   const float* __restrict__ masks,
       const float* __restrict__ kin,    const float* __restrict__ text,
       const float* __restrict__ proto,  const float* __restrict__ w_q,
       const float* __restrict__ w_k,    const float* __restrict__ w_bl,
       const float* __restrict__ w_proj, const float* __restrict__ b_proj,
       float* __restrict__ ws, float* __restrict__ out)
{
    __shared__ __align__(16) char smem[39984];
    int* cnt = (int*)(ws + OFF_CNT);
    const int tid  = threadIdx.x;
    const int bid  = blockIdx.x;
    const int lane = tid & 63, wv = tid >> 6;

    // ================= phase A: pool^2 -> atomic SN2 planes =================
    {
        float*  mk  = (float*) smem;             // 1428 floats
        float2* raw = (float2*)(smem + 5712);    // 1428 float2
        float2* h5s = (float2*)(smem + 17136);
        float2* h7s = (float2*)(smem + 28560);

        int orow[4], ox[4]; bool ov[4];
        #pragma unroll
        for (int j = 0; j < 4; ++j) {
            int o = tid + 256 * j;
            int oy = o / 60, x = o - 60 * oy;
            orow[j] = oy + 3; ox[j] = x; ov[j] = o < 900;
        }
        int lr[5], lx[5]; bool la[5];
        #pragma unroll
        for (int j = 0; j < 5; ++j) {
            int idx = tid + 256 * j;
            int r = idx / 60, x = idx - 60 * r;
            lr[j] = r; lx[j] = x; la[j] = idx < 1260;
        }

        #pragma unroll
        for (int u = 0; u < 2; ++u) {
            int unit = bid + NBLK * u;           // 0..1023
            int tile = unit & 3, cgi = (unit >> 2) & 127, b = unit >> 9;
            int y0 = tile * TROWS;

            __syncthreads();
            const float2 z2 = {0.f, 0.f};
            for (int i = tid; i < LROWS * LPITCH; i += 256) {
                mk[i] = 0.f; raw[i] = z2; h5s[i] = z2; h7s[i] = z2;
            }
            __syncthreads();

            bool lv[5];
            #pragma unroll
            for (int j = 0; j < 5; ++j) {
                int iy = y0 - 3 + lr[j];
                lv[j] = la[j] && (iy >= 0) && (iy < Hh);
                if (lv[j])
                    mk[lr[j] * LPITCH + 4 + lx[j]] =
                        masks[(size_t)b * MH * MH + (size_t)(iy * 8) * MH + lx[j] * 8];
            }

            float a0[4] = {0,0,0,0}, a1[4] = {0,0,0,0}, a2[4] = {0,0,0,0};

            const float* chbase = supp + ((size_t)b * Cch + (size_t)cgi * CPG) * Ssz + (y0 - 3) * 60;
            float pf0[5], pf1[5];
            #pragma unroll
            for (int j = 0; j < 5; ++j) {
                pf0[j] = lv[j] ? chbase[tid + 256 * j] : 0.f;
                pf1[j] = lv[j] ? chbase[Ssz + tid + 256 * j] : 0.f;
            }

            for (int p = 0; p < CPG / 2; ++p) {
                __syncthreads();
                #pragma unroll
                for (int j = 0; j < 5; ++j)
                    if (lv[j]) {
                        float m = mk[lr[j] * LPITCH + 4 + lx[j]];
                        raw[lr[j] * LPITCH + 4 + lx[j]] = make_float2(pf0[j] * m, pf1[j] * m);
                    }
                __syncthreads();
                #pragma unroll
                for (int j = 0; j < 5; ++j)
                    if (la[j]) {
                        int base = lr[j] * LPITCH + 4 + lx[j];
                        float2 m3 = raw[base - 3], m2 = raw[base - 2], m1 = raw[base - 1];
                        float2 c0 = raw[base], p1 = raw[base + 1], p2 = raw[base + 2], p3 = raw[base + 3];
                        float2 h5, h7;
                        h5.x = m2.x + m1.x + c0.x + p1.x + p2.x;
                        h5.y = m2.y + m1.y + c0.y + p1.y + p2.y;
                        h7.x = h5.x + m3.x + p3.x;
                        h7.y = h5.y + m3.y + p3.y;
                        h5s[base] = h5; h7s[base] = h7;
                    }
                __syncthreads();
                if (p + 1 < CPG / 2) {
                    const float* nb = chbase + (size_t)(2 * p + 2) * Ssz;
                    #pragma unroll
                    for (int j = 0; j < 5; ++j) {
                        pf0[j] = lv[j] ? nb[tid + 256 * j] : 0.f;
                        pf1[j] = lv[j] ? nb[Ssz + tid + 256 * j] : 0.f;
                    }
                }
                #pragma unroll
                for (int j = 0; j < 4; ++j)
                    if (ov[j]) {
                        int base = orow[j] * LPITCH + 4 + ox[j];
                        float2 sa = h5s[base - 2*LPITCH], sb = h5s[base - LPITCH], sc0 = h5s[base];
                        float2 sd = h5s[base + LPITCH], se = h5s[base + 2*LPITCH];
                        float p55x = (sa.x + sb.x + sc0.x + sd.x + se.x) * (1.f / 25.f);
                        float p55y = (sa.y + sb.y + sc0.y + sd.y + se.y) * (1.f / 25.f);
                        float2 ra = raw[base - 3*LPITCH], rb = raw[base - 2*LPITCH], rc = raw[base - LPITCH];
                        float2 rd = raw[base], re = raw[base + LPITCH], rf = raw[base + 2*LPITCH], rg = raw[base + 3*LPITCH];
                        float p71x = (ra.x + rb.x + rc.x + rd.x + re.x + rf.x + rg.x) * (1.f / 7.f);
                        float p71y = (ra.y + rb.y + rc.y + rd.y + re.y + rf.y + rg.y) * (1.f / 7.f);
                        float2 h7v = h7s[base];
                        float p17x = h7v.x * (1.f / 7.f), p17y = h7v.y * (1.f / 7.f);
                        a0[j] += p55x * p55x + p55y * p55y;
                        a1[j] += p71x * p71x + p71y * p71y;
                        a2[j] += p17x * p17x + p17y * p17y;
                    }
            }
            float* acc = ws + OFF_SN2 + (size_t)(b * 3) * Ssz;
            #pragma unroll
            for (int j = 0; j < 4; ++j)
                if (ov[j]) {
                    int q = (y0 + orow[j] - 3) * 60 + ox[j];
                    atomicAdd(&acc[q], a0[j]);
                    atomicAdd(&acc[Ssz + q], a1[j]);
                    atomicAdd(&acc[2 * Ssz + q], a2[j]);
                }
        }
    }

    gbar(cnt, 1);   // SN2 ready

    // ================= phase B: wmap (24 blocks) + u-GEMV chain (2) =========
    if (bid < 24) {
        float* inv = (float*)smem;           // 1428 floats
        int tile = bid & 3, bk = bid >> 2;
        int b = bk / 3, kt = bk % 3;
        int y0 = tile * TROWS;
        for (int i = tid; i < LROWS * LPITCH; i += 256) inv[i] = 0.f;
        __syncthreads();
        const float* pp = ws + OFF_SN2 + (size_t)bk * Ssz;
        #pragma unroll
        for (int j = 0; j < 5; ++j) {
            int idx = tid + 256 * j;
            if (idx < 1260) {
                int r = idx / 60, x = idx - 60 * r;
                int iy = y0 - 3 + r;
                if (iy >= 0 && iy < Hh)
                    inv[r * LPITCH + 4 + x] = 1.0f / sqrtf(fmaxf(pp[iy * 60 + x], 1e-30f));
            }
        }
        __syncthreads();
        int kh = (kt == 0) ? 5 : (kt == 1) ? 7 : 1;
        int kw = (kt == 0) ? 5 : (kt == 2) ? 7 : 1;
        int rh = kh / 2, rw = kw / 2;
        float norm = 1.f / (float)(kh * kw);
        #pragma unroll
        for (int j = 0; j < 4; ++j) {
            int o = tid + 256 * j;
            if (o < 900) {
                int oy = o / 60, x = o - 60 * oy;
                int base = (oy + 3) * LPITCH + 4 + x;
                float s = 0.f;
                for (int dy = -rh; dy <= rh; ++dy)
                    for (int dx = -rw; dx <= rw; ++dx)
                        s += inv[base + dy * LPITCH + dx];
                int gy = y0 + oy;
                float m = masks[(size_t)b * MH * MH + (size_t)(gy * 8) * MH + x * 8];
                ws[OFF_WMAP + (size_t)bk * Ssz + gy * 60 + x] = s * norm * m;
            }
        }
    } else if (bid < 26) {
        // u = w_k^T (w_bl^T (w_q^T [text;proto]))
        int b = bid - 24;
        float* xs  = (float*)smem;           // 556
        float* qxs = (float*)(smem + 2240);  // 256
        float* qws = (float*)(smem + 3264);  // 256
        #pragma unroll
        for (int j = 0; j < 3; ++j) {
            int e = tid + 256 * j;
            if (e < TDIM) xs[e] = text[b * TDIM + e];
            else if (e < TDIM + HID) xs[e] = proto[b * HID + e - TDIM];
        }
        __syncthreads();
        float a = 0.f;
        #pragma unroll 4
        for (int e = 0; e < TDIM + HID; ++e) a += xs[e] * w_q[(size_t)e * HID + tid];
        qxs[tid] = a;
        __syncthreads();
        a = 0.f;
        #pragma unroll 4
        for (int e = 0; e < HID; ++e) a += qxs[e] * w_bl[(size_t)e * HID + tid];
        qws[tid] = a;
        __syncthreads();
        a = 0.f;
        #pragma unroll 4
        for (int e = 0; e < HID; ++e) a += qws[e] * w_k[(size_t)e * HID + tid];
        ws[OFF_U + b * HID + tid] = a;
    }

    gbar(cnt, 2);   // WMAP + U ready

    // ================= phase C: v[b][kt][c] (all 512 blocks) ================
    {
        int cB = bid & 255, b = bid >> 8;
        int c0 = cB * 4;
        const float4* sp4 = (const float4*)(supp + ((size_t)b * Cch + c0) * Ssz);
        const float4* w04 = (const float4*)(ws + OFF_WMAP + (size_t)(b * 3 + 0) * Ssz);
        const float4* w14 = (const float4*)(ws + OFF_WMAP + (size_t)(b * 3 + 1) * Ssz);
        const float4* w24 = (const float4*)(ws + OFF_WMAP + (size_t)(b * 3 + 2) * Ssz);
        float a[4][3];
        #pragma unroll
        for (int cc = 0; cc < 4; ++cc) { a[cc][0] = 0; a[cc][1] = 0; a[cc][2] = 0; }
        #pragma unroll
        for (int j = 0; j < 4; ++j) {
            int idx = tid + 256 * j;
            if (idx < 900) {
                float4 g0 = w04[idx], g1 = w14[idx], g2 = w24[idx];
                #pragma unroll
                for (int cc = 0; cc < 4; ++cc) {
                    float4 f = sp4[cc * 900 + idx];
                    a[cc][0] += f.x * g0.x + f.y * g0.y + f.z * g0.z + f.w * g0.w;
                    a[cc][1] += f.x * g1.x + f.y * g1.y + f.z * g1.z + f.w * g1.w;
                    a[cc][2] += f.x * g2.x + f.y * g2.y + f.z * g2.z + f.w * g2.w;
                }
            }
        }
        #pragma unroll
        for (int m = 32; m >= 1; m >>= 1)
            #pragma unroll
            for (int cc = 0; cc < 4; ++cc) {
                a[cc][0] += __shfl_xor(a[cc][0], m, 64);
                a[cc][1] += __shfl_xor(a[cc][1], m, 64);
                a[cc][2] += __shfl_xor(a[cc][2], m, 64);
            }
        float* r = (float*)smem;             // [4][3][4]
        if (lane == 0)
            #pragma unroll
            for (int cc = 0; cc < 4; ++cc) {
                r[(cc * 3 + 0) * 4 + wv] = a[cc][0];
                r[(cc * 3 + 1) * 4 + wv] = a[cc][1];
                r[(cc * 3 + 2) * 4 + wv] = a[cc][2];
            }
        __syncthreads();
        if (tid < 12) {
            int cc = tid / 3, kk = tid - cc * 3;
            float s = r[(cc * 3 + kk) * 4 + 0] + r[(cc * 3 + kk) * 4 + 1]
                    + r[(cc * 3 + kk) * 4 + 2] + r[(cc * 3 + kk) * 4 + 3];
            ws[OFF_V + (size_t)(b * 3 + kk) * Cch + c0 + cc] = s;
        }
    }

    gbar(cnt, 3);   // V ready

    // ================= phase D: dot planes (480 blocks, atomic) =============
    if (bid < 480) {
        int qt = bid % 15, cc = (bid / 15) & 15, b = bid / 240;
        int q = qt * 256 + tid;
        if (q < Ssz) {
            const float* v0 = ws + OFF_V + (size_t)(b * 3 + 0) * Cch;
            const float* v1 = ws + OFF_V + (size_t)(b * 3 + 1) * Cch;
            const float* v2 = ws + OFF_V + (size_t)(b * 3 + 2) * Cch;
            float a0 = 0, a1 = 0, a2 = 0;
            int c0 = cc * 64;
            #pragma unroll 8
            for (int c = c0; c < c0 + 64; ++c) {
                float qv = query[((size_t)b * Cch + c) * Ssz + q];
                a0 += qv * v0[c]; a1 += qv * v1[c]; a2 += qv * v2[c];
            }
            float* dst = ws + OFF_DOT + (size_t)(b * 3) * Ssz + q;
            atomicAdd(&dst[0], a0);
            atomicAdd(&dst[Ssz], a1);
            atomicAdd(&dst[2 * Ssz], a2);
        }
    }

    gbar(cnt, 4);   // DOT ready

    // ================= phase E: sim (6 blocks) + score (30 blocks) ==========
    if (bid < 6) {
        float* sA  = (float*)smem;               // 4488 floats
        float* sB  = (float*)(smem + 17952);     // 4488 floats
        float* rmn = (float*)(smem + 35904);     // 4
        float* rmx = (float*)(smem + 35936);     // 4
        int kt = bid % 3;
        const float* dp0 = ws + OFF_DOT + (size_t)bid * Ssz;
        for (int i = tid; i < 66 * LPITCH; i += 256) {
            int r = i / LPITCH, col = i - r * LPITCH;
            int y = r - 3, x = col - 4;
            float s = 0.f;
            if (y >= 0 && y < Hh && x >= 0 && x < Hh) s = dp0[y * Hh + x];
            sA[i] = s;
        }
        __syncthreads();
        if (kt != 1) {
            for (int idx = tid; idx < 66 * 60; idx += 256) {
                int r = idx / 60, x = idx - 60 * r;
                int base = r * LPITCH + 4 + x;
                if (kt == 0)
                    sB[base] = sA[base - 2] + sA[base - 1] + sA[base] + sA[base + 1] + sA[base + 2];
                else
                    sB[base] = sA[base - 3] + sA[base - 2] + sA[base - 1] + sA[base]
                             + sA[base + 1] + sA[base + 2] + sA[base + 3];
            }
        }
        __syncthreads();
        float norm = ((kt == 0) ? (1.f / 25.f) : (1.f / 7.f)) * (1.f / (float)Ssz);
        float vals[15];
        float vmin = INFINITY, vmax = -INFINITY;
        #pragma unroll
        for (int j = 0; j < 15; ++j) {
            int q = tid + j * 256;
            if (q < Ssz) {
                int y = q / Hh, x = q - y * Hh;
                int base = (y + 3) * LPITCH + 4 + x;
                float s;
                if (kt == 0)
                    s = sB[base - 2*LPITCH] + sB[base - LPITCH] + sB[base]
                      + sB[base + LPITCH] + sB[base + 2*LPITCH];
                else if (kt == 1)
                    s = sA[base - 3*LPITCH] + sA[base - 2*LPITCH] + sA[base - LPITCH]
                      + sA[base] + sA[base + LPITCH] + sA[base + 2*LPITCH] + sA[base + 3*LPITCH];
                else
                    s = sB[base];
                float val = s * norm;
                vals[j] = val;
                vmin = fminf(vmin, val); vmax = fmaxf(vmax, val);
            }
        }
        #pragma unroll
        for (int m = 32; m >= 1; m >>= 1) {
            vmin = fminf(vmin, __shfl_xor(vmin, m, 64));
            vmax = fmaxf(vmax, __shfl_xor(vmax, m, 64));
        }
        if (lane == 0) { rmn[wv] = vmin; rmx[wv] = vmax; }
        __syncthreads();
        float mn = fminf(fminf(rmn[0], rmn[1]), fminf(rmn[2], rmn[3]));
        float mx = fmaxf(fmaxf(rmx[0], rmx[1]), fmaxf(rmx[2], rmx[3]));
        float inv = 1.f / (mx - mn + EPSF);
        float* np = ws + OFF_NORM + (size_t)bid * Ssz;
        #pragma unroll
        for (int j = 0; j < 15; ++j) {
            int q = tid + j * 256;
            if (q < Ssz) np[q] = (vals[j] - mn) * inv;
        }
    } else if (bid < 36) {
        int u2 = bid - 6, st = u2 % 15, b = u2 / 15;
        float* us = (float*)smem;                // 256
        us[tid] = ws[OFF_U + b * HID + tid];
        __syncthreads();
        int s = st * 256 + tid;
        if (s < Ssz) {
            const float* kb = kin + (size_t)b * HID * Ssz + s;
            float a = 0.f;
            #pragma unroll 8
            for (int i = 0; i < HID; ++i) a += us[i] * kb[(size_t)i * Ssz];
            ws[OFF_SCORE + (size_t)b * Ssz + s] = a;
        }
    }

    gbar(cnt, 5);   // NORM + SCORE ready

    // ================= phase F: kbar (512 blocks) ===========================
    {
        int i = bid & 255, b = bid >> 8;
        float* r1 = (float*)smem;
        float* r2 = (float*)(smem + 32);
        const float4* s4 = (const float4*)(ws + OFF_SCORE + (size_t)b * Ssz);
        float4 sv[4]; bool act[4];
        float mx = -INFINITY;
        #pragma unroll
        for (int j = 0; j < 4; ++j) {
            int idx = tid + 256 * j;
            act[j] = idx < 900;
            if (act[j]) {
                float4 v = s4[idx];
                sv[j] = v;
                mx = fmaxf(mx, fmaxf(fmaxf(v.x, v.y), fmaxf(v.z, v.w)));
            }
        }
        #pragma unroll
        for (int m = 32; m >= 1; m >>= 1) mx = fmaxf(mx, __shfl_xor(mx, m, 64));
        if (lane == 0) r1[wv] = mx;
        __syncthreads();
        mx = fmaxf(fmaxf(r1[0], r1[1]), fmaxf(r1[2], r1[3]));
        __syncthreads();
        const float4* kr = (const float4*)(kin + ((size_t)b * HID + i) * Ssz);
        float se = 0.f, wsum = 0.f;
        #pragma unroll
        for (int j = 0; j < 4; ++j) {
            if (act[j]) {
                int idx = tid + 256 * j;
                float4 v = sv[j];
                float ex = expf(v.x - mx), ey = expf(v.y - mx);
                float ez = expf(v.z - mx), ew = expf(v.w - mx);
                se += ex + ey + ez + ew;
                float4 k4 = kr[idx];
                wsum += ex * k4.x + ey * k4.y + ez * k4.z + ew * k4.w;
            }
        }
        #pragma unroll
        for (int m = 32; m >= 1; m >>= 1) {
            se += __shfl_xor(se, m, 64);
            wsum += __shfl_xor(wsum, m, 64);
        }
        if (lane == 0) { r1[wv] = se; r2[wv] = wsum; }
        __syncthreads();
        if (tid == 0) {
            float seT = r1[0] + r1[1] + r1[2] + r1[3];
            float wsT = r2[0] + r2[1] + r2[2] + r2[3];
            ws[OFF_KBAR + b * HID + i] = wsT / seT;
        }
    }

    gbar(cnt, 6);   // KBAR ready

    // ================= phase G: apa-out (2) + corr-final (2) ================
    if (bid < 2) {
        int b = bid;
        float4* kbs = (float4*)smem;             // 64 float4
        float*  o1s = (float*)(smem + 1024);     // 256
        if (tid < 64) kbs[tid] = ((const float4*)(ws + OFF_KBAR + b * HID))[tid];
        __syncthreads();
        float4 kb4 = kbs[lane];
        const float4* wk4 = (const float4*)w_k;
        #pragma unroll 8
        for (int r = 0; r < 64; ++r) {
            int h = wv * 64 + r;
            float4 f = wk4[(size_t)h * 64 + lane];
            float p = f.x * kb4.x + f.y * kb4.y + f.z * kb4.z + f.w * kb4.w;
            #pragma unroll
            for (int m = 32; m >= 1; m >>= 1) p += __shfl_xor(p, m, 64);
            if (lane == 0) o1s[h] = p;
        }
        __syncthreads();
        float a = 0.f;
        #pragma unroll 4
        for (int d = 0; d < HID; ++d) a += o1s[d] * w_proj[(size_t)d * HID + tid];
        out[9578 + b * HID + tid] = a + b_proj[tid] + proto[b * HID + tid];
    } else if (bid < 4) {
        int b = bid - 2;
        float* sF = (float*)smem;                // 3600 floats
        float wq3 = weight[b] * (1.f / 3.f);
        const float* n0 = ws + OFF_NORM + (size_t)(b * 3) * Ssz;
        #pragma unroll
        for (int j = 0; j < 15; ++j) {
            int q = tid + j * 256;
            if (q < Ssz) {
                float s = n0[q] + n0[Ssz + q] + n0[2 * Ssz + q];
                sF[q] = s;
                out[b * Ssz + q] = wq3 * s;
            }
        }
        __syncthreads();
        #pragma unroll
        for (int j = 0; j < 5; ++j) {
            int o = tid + j * 256;
            if (o >= 1189) continue;
            int O, p, outi;
            if (o < 900)       { O = 30; p = o;        outi = 7200 + b * 900 + p; }
            else if (o < 1125) { O = 15; p = o - 900;  outi = 9000 + b * 225 + p; }
            else               { O = 8;  p = o - 1125; outi = 9450 + b * 64 + p; }
            int y = p / O, x = p - y * O;
            float sc = 59.f / (float)(O - 1);
            float py = y * sc, px = x * sc;
            int y0 = (int)floorf(py), x0 = (int)floorf(px);
            int y1 = min(y0 + 1, 59), x1 = min(x0 + 1, 59);
            float wy = py - y0, wx = px - x0;
            float v = sF[y0 * 60 + x0] * (1.f - wy) * (1.f - wx)
                    + sF[y1 * 60 + x0] * wy * (1.f - wx)
                    + sF[y0 * 60 + x1] * (1.f - wy) * wx
                    + sF[y1 * 60 + x1] * wy * wx;
            out[outi] = wq3 * v;
        }
    }
}

extern "C" void kernel_launch(void* const* d_in, const int* in_sizes, int n_in,
                              void* d_out, int out_size, void* d_ws, size_t ws_size,
                              hipStream_t stream) {
    const float* weight = (const float*)d_in[0];
    const float* query  = (const float*)d_in[1];
    const float* supp   = (const float*)d_in[2];
    const float* masks  = (const float*)d_in[3];
    const float* kin    = (const float*)d_in[4];
    const float* text   = (const float*)d_in[5];
    const float* proto  = (const float*)d_in[6];
    const float* w_q    = (const float*)d_in[7];
    const float* w_k    = (const float*)d_in[8];
    const float* w_bl   = (const float*)d_in[9];
    const float* w_proj = (const float*)d_in[10];
    const float* b_proj = (const float*)d_in[11];
    float* out = (float*)d_out;
    float* ws  = (float*)d_ws;

    // zero atomic planes + barrier counter (stream-ordered before kernel)
    hipMemsetAsync(ws, 0, (size_t)(OFF_CNT + 16) * sizeof(float), stream);

    k_mega<<<dim3(NBLK), dim3(256), 0, stream>>>(
        weight, query, supp, masks, kin, text, proto,
        w_q, w_k, w_bl, w_proj, b_proj, ws, out);
}

// Round 4
// 475.134 us; speedup vs baseline: 1.9534x; 1.9534x over previous
//
#include <hip/hip_runtime.h>
#include <math.h>

#define EPSF 1e-7f
#define Bsz 2
#define Cch 1024
#define Hh 60
#define Ssz 3600
#define HID 256
#define TDIM 300
#define MH 473

// pool tiling
#define TROWS 15
#define LROWS 21          // TROWS + 6 halo
#define LPITCH 68         // 4-col zero pad both sides of 60 cols
#define CPG 8             // channels per block (processed as 4 float2 pairs)

// workspace layout (float offsets)
// [0, 43216) zeroed by hipMemsetAsync each launch (SN2 + DOT planes + barrier cnt)
#define OFF_SN2    0               // 6*3600 sum over channels of pool^2 (atomic)
#define OFF_DOT    21600           // 6*3600 dot planes (atomic)
#define OFF_CNT    43200           // 16 (barrier counter in [0])
#define OFF_WMAP   43216           // 6*3600  mask-premultiplied pool(1/sn)
#define OFF_V      64816           // 6*1024
#define OFF_NORM   70960           // 6*3600 normalized sim planes
#define OFF_SCORE  92560           // 2*3600
#define OFF_KBAR   99760           // 2*256
#define OFF_U      100272          // 2*256

#define NBLK 512

// software grid barrier, ROCm __ockl_grid_sync style:
// release-add once; RELAXED spin (no per-iteration cache invalidate!);
// single ACQUIRE load after exit. The previous ACQUIRE-spin version
// triggered an L2-invalidation storm (858us, VALUBusy 1%).
__device__ __forceinline__ void gbar(int* cnt, int round) {
    __syncthreads();
    if (threadIdx.x == 0) {
        __hip_atomic_fetch_add(cnt, 1, __ATOMIC_RELEASE, __HIP_MEMORY_SCOPE_AGENT);
        while (__hip_atomic_load(cnt, __ATOMIC_RELAXED, __HIP_MEMORY_SCOPE_AGENT)
               < NBLK * round)
            __builtin_amdgcn_s_sleep(8);
        (void)__hip_atomic_load(cnt, __ATOMIC_ACQUIRE, __HIP_MEMORY_SCOPE_AGENT);
    }
    __syncthreads();
}

__global__ void __launch_bounds__(256, 2)
k_mega(const float* __restrict__ weight, const float* __restrict__ query,
       const float* __restrict__ supp,   const float* __restrict__ masks,
       const float* __restrict__ kin,    const float* __restrict__ text,
       const float* __restrict__ proto,  const float* __restrict__ w_q,
       const float* __restrict__ w_k,    const float* __restrict__ w_bl,
       const float* __restrict__ w_proj, const float* __restrict__ b_proj,
       float* __restrict__ ws, float* __restrict__ out)
{
    __shared__ __align__(16) char smem[39984];
    int* cnt = (int*)(ws + OFF_CNT);
    const int tid  = threadIdx.x;
    const int bid  = blockIdx.x;
    const int lane = tid & 63, wv = tid >> 6;

    // ================= phase A: pool^2 -> atomic SN2 planes =================
    {
        float*  mk  = (float*) smem;             // 1428 floats
        float2* raw = (float2*)(smem + 5712);    // 1428 float2
        float2* h5s = (float2*)(smem + 17136);
        float2* h7s = (float2*)(smem + 28560);

        int orow[4], ox[4]; bool ov[4];
        #pragma unroll
        for (int j = 0; j < 4; ++j) {
            int o = tid + 256 * j;
            int oy = o / 60, x = o - 60 * oy;
            orow[j] = oy + 3; ox[j] = x; ov[j] = o < 900;
        }
        int lr[5], lx[5]; bool la[5];
        #pragma unroll
        for (int j = 0; j < 5; ++j) {
            int idx = tid + 256 * j;
            int r = idx / 60, x = idx - 60 * r;
            lr[j] = r; lx[j] = x; la[j] = idx < 1260;
        }

        #pragma unroll
        for (int u = 0; u < 2; ++u) {
            int unit = bid + NBLK * u;           // 0..1023
            int tile = unit & 3, cgi = (unit >> 2) & 127, b = unit >> 9;
            int y0 = tile * TROWS;

            __syncthreads();
            const float2 z2 = {0.f, 0.f};
            for (int i = tid; i < LROWS * LPITCH; i += 256) {
                mk[i] = 0.f; raw[i] = z2; h5s[i] = z2; h7s[i] = z2;
            }
            __syncthreads();

            bool lv[5];
            #pragma unroll
            for (int j = 0; j < 5; ++j) {
                int iy = y0 - 3 + lr[j];
                lv[j] = la[j] && (iy >= 0) && (iy < Hh);
                if (lv[j])
                    mk[lr[j] * LPITCH + 4 + lx[j]] =
                        masks[(size_t)b * MH * MH + (size_t)(iy * 8) * MH + lx[j] * 8];
            }

            float a0[4] = {0,0,0,0}, a1[4] = {0,0,0,0}, a2[4] = {0,0,0,0};

            const float* chbase = supp + ((size_t)b * Cch + (size_t)cgi * CPG) * Ssz + (y0 - 3) * 60;
            float pf0[5], pf1[5];
            #pragma unroll
            for (int j = 0; j < 5; ++j) {
                pf0[j] = lv[j] ? chbase[tid + 256 * j] : 0.f;
                pf1[j] = lv[j] ? chbase[Ssz + tid + 256 * j] : 0.f;
            }

            for (int p = 0; p < CPG / 2; ++p) {
                __syncthreads();
                #pragma unroll
                for (int j = 0; j < 5; ++j)
                    if (lv[j]) {
                        float m = mk[lr[j] * LPITCH + 4 + lx[j]];
                        raw[lr[j] * LPITCH + 4 + lx[j]] = make_float2(pf0[j] * m, pf1[j] * m);
                    }
                __syncthreads();
                #pragma unroll
                for (int j = 0; j < 5; ++j)
                    if (la[j]) {
                        int base = lr[j] * LPITCH + 4 + lx[j];
                        float2 m3 = raw[base - 3], m2 = raw[base - 2], m1 = raw[base - 1];
                        float2 c0 = raw[base], p1 = raw[base + 1], p2 = raw[base + 2], p3 = raw[base + 3];
                        float2 h5, h7;
                        h5.x = m2.x + m1.x + c0.x + p1.x + p2.x;
                        h5.y = m2.y + m1.y + c0.y + p1.y + p2.y;
                        h7.x = h5.x + m3.x + p3.x;
                        h7.y = h5.y + m3.y + p3.y;
                        h5s[base] = h5; h7s[base] = h7;
                    }
                __syncthreads();
                if (p + 1 < CPG / 2) {
                    const float* nb = chbase + (size_t)(2 * p + 2) * Ssz;
                    #pragma unroll
                    for (int j = 0; j < 5; ++j) {
                        pf0[j] = lv[j] ? nb[tid + 256 * j] : 0.f;
                        pf1[j] = lv[j] ? nb[Ssz + tid + 256 * j] : 0.f;
                    }
                }
                #pragma unroll
                for (int j = 0; j < 4; ++j)
                    if (ov[j]) {
                        int base = orow[j] * LPITCH + 4 + ox[j];
                        float2 sa = h5s[base - 2*LPITCH], sb = h5s[base - LPITCH], sc0 = h5s[base];
                        float2 sd = h5s[base + LPITCH], se = h5s[base + 2*LPITCH];
                        float p55x = (sa.x + sb.x + sc0.x + sd.x + se.x) * (1.f / 25.f);
                        float p55y = (sa.y + sb.y + sc0.y + sd.y + se.y) * (1.f / 25.f);
                        float2 ra = raw[base - 3*LPITCH], rb = raw[base - 2*LPITCH], rc = raw[base - LPITCH];
                        float2 rd = raw[base], re = raw[base + LPITCH], rf = raw[base + 2*LPITCH], rg = raw[base + 3*LPITCH];
                        float p71x = (ra.x + rb.x + rc.x + rd.x + re.x + rf.x + rg.x) * (1.f / 7.f);
                        float p71y = (ra.y + rb.y + rc.y + rd.y + re.y + rf.y + rg.y) * (1.f / 7.f);
                        float2 h7v = h7s[base];
                        float p17x = h7v.x * (1.f / 7.f), p17y = h7v.y * (1.f / 7.f);
                        a0[j] += p55x * p55x + p55y * p55y;
                        a1[j] += p71x * p71x + p71y * p71y;
                        a2[j] += p17x * p17x + p17y * p17y;
                    }
            }
            float* acc = ws + OFF_SN2 + (size_t)(b * 3) * Ssz;
            #pragma unroll
            for (int j = 0; j < 4; ++j)
                if (ov[j]) {
                    int q = (y0 + orow[j] - 3) * 60 + ox[j];
                    atomicAdd(&acc[q], a0[j]);
                    atomicAdd(&acc[Ssz + q], a1[j]);
                    atomicAdd(&acc[2 * Ssz + q], a2[j]);
                }
        }
    }

    gbar(cnt, 1);   // SN2 ready

    // ================= phase B: wmap (24 blocks) + u-GEMV chain (2) =========
    if (bid < 24) {
        float* inv = (float*)smem;           // 1428 floats
        int tile = bid & 3, bk = bid >> 2;
        int b = bk / 3, kt = bk % 3;
        int y0 = tile * TROWS;
        for (int i = tid; i < LROWS * LPITCH; i += 256) inv[i] = 0.f;
        __syncthreads();
        const float* pp = ws + OFF_SN2 + (size_t)bk * Ssz;
        #pragma unroll
        for (int j = 0; j < 5; ++j) {
            int idx = tid + 256 * j;
            if (idx < 1260) {
                int r = idx / 60, x = idx - 60 * r;
                int iy = y0 - 3 + r;
                if (iy >= 0 && iy < Hh)
                    inv[r * LPITCH + 4 + x] = 1.0f / sqrtf(fmaxf(pp[iy * 60 + x], 1e-30f));
            }
        }
        __syncthreads();
        int kh = (kt == 0) ? 5 : (kt == 1) ? 7 : 1;
        int kw = (kt == 0) ? 5 : (kt == 2) ? 7 : 1;
        int rh = kh / 2, rw = kw / 2;
        float norm = 1.f / (float)(kh * kw);
        #pragma unroll
        for (int j = 0; j < 4; ++j) {
            int o = tid + 256 * j;
            if (o < 900) {
                int oy = o / 60, x = o - 60 * oy;
                int base = (oy + 3) * LPITCH + 4 + x;
                float s = 0.f;
                for (int dy = -rh; dy <= rh; ++dy)
                    for (int dx = -rw; dx <= rw; ++dx)
                        s += inv[base + dy * LPITCH + dx];
                int gy = y0 + oy;
                float m = masks[(size_t)b * MH * MH + (size_t)(gy * 8) * MH + x * 8];
                ws[OFF_WMAP + (size_t)bk * Ssz + gy * 60 + x] = s * norm * m;
            }
        }
    } else if (bid < 26) {
        // u = w_k^T (w_bl^T (w_q^T [text;proto]))
        int b = bid - 24;
        float* xs  = (float*)smem;           // 556
        float* qxs = (float*)(smem + 2240);  // 256
        float* qws = (float*)(smem + 3264);  // 256
        #pragma unroll
        for (int j = 0; j < 3; ++j) {
            int e = tid + 256 * j;
            if (e < TDIM) xs[e] = text[b * TDIM + e];
            else if (e < TDIM + HID) xs[e] = proto[b * HID + e - TDIM];
        }
        __syncthreads();
        float a = 0.f;
        #pragma unroll 4
        for (int e = 0; e < TDIM + HID; ++e) a += xs[e] * w_q[(size_t)e * HID + tid];
        qxs[tid] = a;
        __syncthreads();
        a = 0.f;
        #pragma unroll 4
        for (int e = 0; e < HID; ++e) a += qxs[e] * w_bl[(size_t)e * HID + tid];
        qws[tid] = a;
        __syncthreads();
        a = 0.f;
        #pragma unroll 4
        for (int e = 0; e < HID; ++e) a += qws[e] * w_k[(size_t)e * HID + tid];
        ws[OFF_U + b * HID + tid] = a;
    }

    gbar(cnt, 2);   // WMAP + U ready

    // ================= phase C: v[b][kt][c] (all 512 blocks) ================
    {
        int cB = bid & 255, b = bid >> 8;
        int c0 = cB * 4;
        const float4* sp4 = (const float4*)(supp + ((size_t)b * Cch + c0) * Ssz);
        const float4* w04 = (const float4*)(ws + OFF_WMAP + (size_t)(b * 3 + 0) * Ssz);
        const float4* w14 = (const float4*)(ws + OFF_WMAP + (size_t)(b * 3 + 1) * Ssz);
        const float4* w24 = (const float4*)(ws + OFF_WMAP + (size_t)(b * 3 + 2) * Ssz);
        float a[4][3];
        #pragma unroll
        for (int cc = 0; cc < 4; ++cc) { a[cc][0] = 0; a[cc][1] = 0; a[cc][2] = 0; }
        #pragma unroll
        for (int j = 0; j < 4; ++j) {
            int idx = tid + 256 * j;
            if (idx < 900) {
                float4 g0 = w04[idx], g1 = w14[idx], g2 = w24[idx];
                #pragma unroll
                for (int cc = 0; cc < 4; ++cc) {
                    float4 f = sp4[cc * 900 + idx];
                    a[cc][0] += f.x * g0.x + f.y * g0.y + f.z * g0.z + f.w * g0.w;
                    a[cc][1] += f.x * g1.x + f.y * g1.y + f.z * g1.z + f.w * g1.w;
                    a[cc][2] += f.x * g2.x + f.y * g2.y + f.z * g2.z + f.w * g2.w;
                }
            }
        }
        #pragma unroll
        for (int m = 32; m >= 1; m >>= 1)
            #pragma unroll
            for (int cc = 0; cc < 4; ++cc) {
                a[cc][0] += __shfl_xor(a[cc][0], m, 64);
                a[cc][1] += __shfl_xor(a[cc][1], m, 64);
                a[cc][2] += __shfl_xor(a[cc][2], m, 64);
            }
        float* r = (float*)smem;             // [4][3][4]
        if (lane == 0)
            #pragma unroll
            for (int cc = 0; cc < 4; ++cc) {
                r[(cc * 3 + 0) * 4 + wv] = a[cc][0];
                r[(cc * 3 + 1) * 4 + wv] = a[cc][1];
                r[(cc * 3 + 2) * 4 + wv] = a[cc][2];
            }
        __syncthreads();
        if (tid < 12) {
            int cc = tid / 3, kk = tid - cc * 3;
            float s = r[(cc * 3 + kk) * 4 + 0] + r[(cc * 3 + kk) * 4 + 1]
                    + r[(cc * 3 + kk) * 4 + 2] + r[(cc * 3 + kk) * 4 + 3];
            ws[OFF_V + (size_t)(b * 3 + kk) * Cch + c0 + cc] = s;
        }
    }

    gbar(cnt, 3);   // V ready

    // ================= phase D: dot planes (480 blocks, atomic) =============
    if (bid < 480) {
        int qt = bid % 15, cc = (bid / 15) & 15, b = bid / 240;
        int q = qt * 256 + tid;
        if (q < Ssz) {
            const float* v0 = ws + OFF_V + (size_t)(b * 3 + 0) * Cch;
            const float* v1 = ws + OFF_V + (size_t)(b * 3 + 1) * Cch;
            const float* v2 = ws + OFF_V + (size_t)(b * 3 + 2) * Cch;
            float a0 = 0, a1 = 0, a2 = 0;
            int c0 = cc * 64;
            #pragma unroll 8
            for (int c = c0; c < c0 + 64; ++c) {
                float qv = query[((size_t)b * Cch + c) * Ssz + q];
                a0 += qv * v0[c]; a1 += qv * v1[c]; a2 += qv * v2[c];
            }
            float* dst = ws + OFF_DOT + (size_t)(b * 3) * Ssz + q;
            atomicAdd(&dst[0], a0);
            atomicAdd(&dst[Ssz], a1);
            atomicAdd(&dst[2 * Ssz], a2);
        }
    }

    gbar(cnt, 4);   // DOT ready

    // ================= phase E: sim (6 blocks) + score (30 blocks) ==========
    if (bid < 6) {
        float* sA  = (float*)smem;               // 4488 floats
        float* sB  = (float*)(smem + 17952);     // 4488 floats
        float* rmn = (float*)(smem + 35904);     // 4
        float* rmx = (float*)(smem + 35936);     // 4
        int kt = bid % 3;
        const float* dp0 = ws + OFF_DOT + (size_t)bid * Ssz;
        for (int i = tid; i < 66 * LPITCH; i += 256) {
            int r = i / LPITCH, col = i - r * LPITCH;
            int y = r - 3, x = col - 4;
            float s = 0.f;
            if (y >= 0 && y < Hh && x >= 0 && x < Hh) s = dp0[y * Hh + x];
            sA[i] = s;
        }
        __syncthreads();
        if (kt != 1) {
            for (int idx = tid; idx < 66 * 60; idx += 256) {
                int r = idx / 60, x = idx - 60 * r;
                int base = r * LPITCH + 4 + x;
                if (kt == 0)
                    sB[base] = sA[base - 2] + sA[base - 1] + sA[base] + sA[base + 1] + sA[base + 2];
                else
                    sB[base] = sA[base - 3] + sA[base - 2] + sA[base - 1] + sA[base]
                             + sA[base + 1] + sA[base + 2] + sA[base + 3];
            }
        }
        __syncthreads();
        float norm = ((kt == 0) ? (1.f / 25.f) : (1.f / 7.f)) * (1.f / (float)Ssz);
        float vals[15];
        float vmin = INFINITY, vmax = -INFINITY;
        #pragma unroll
        for (int j = 0; j < 15; ++j) {
            int q = tid + j * 256;
            if (q < Ssz) {
                int y = q / Hh, x = q - y * Hh;
                int base = (y + 3) * LPITCH + 4 + x;
                float s;
                if (kt == 0)
                    s = sB[base - 2*LPITCH] + sB[base - LPITCH] + sB[base]
                      + sB[base + LPITCH] + sB[base + 2*LPITCH];
                else if (kt == 1)
                    s = sA[base - 3*LPITCH] + sA[base - 2*LPITCH] + sA[base - LPITCH]
                      + sA[base] + sA[base + LPITCH] + sA[base + 2*LPITCH] + sA[base + 3*LPITCH];
                else
                    s = sB[base];
                float val = s * norm;
                vals[j] = val;
                vmin = fminf(vmin, val); vmax = fmaxf(vmax, val);
            }
        }
        #pragma unroll
        for (int m = 32; m >= 1; m >>= 1) {
            vmin = fminf(vmin, __shfl_xor(vmin, m, 64));
            vmax = fmaxf(vmax, __shfl_xor(vmax, m, 64));
        }
        if (lane == 0) { rmn[wv] = vmin; rmx[wv] = vmax; }
        __syncthreads();
        float mn = fminf(fminf(rmn[0], rmn[1]), fminf(rmn[2], rmn[3]));
        float mx = fmaxf(fmaxf(rmx[0], rmx[1]), fmaxf(rmx[2], rmx[3]));
        float inv = 1.f / (mx - mn + EPSF);
        float* np = ws + OFF_NORM + (size_t)bid * Ssz;
        #pragma unroll
        for (int j = 0; j < 15; ++j) {
            int q = tid + j * 256;
            if (q < Ssz) np[q] = (vals[j] - mn) * inv;
        }
    } else if (bid < 36) {
        int u2 = bid - 6, st = u2 % 15, b = u2 / 15;
        float* us = (float*)smem;                // 256
        us[tid] = ws[OFF_U + b * HID + tid];
        __syncthreads();
        int s = st * 256 + tid;
        if (s < Ssz) {
            const float* kb = kin + (size_t)b * HID * Ssz + s;
            float a = 0.f;
            #pragma unroll 8
            for (int i = 0; i < HID; ++i) a += us[i] * kb[(size_t)i * Ssz];
            ws[OFF_SCORE + (size_t)b * Ssz + s] = a;
        }
    }

    gbar(cnt, 5);   // NORM + SCORE ready

    // ================= phase F: kbar (512 blocks) ===========================
    {
        int i = bid & 255, b = bid >> 8;
        float* r1 = (float*)smem;
        float* r2 = (float*)(smem + 32);
        const float4* s4 = (const float4*)(ws + OFF_SCORE + (size_t)b * Ssz);
        float4 sv[4]; bool act[4];
        float mx = -INFINITY;
        #pragma unroll
        for (int j = 0; j < 4; ++j) {
            int idx = tid + 256 * j;
            act[j] = idx < 900;
            if (act[j]) {
                float4 v = s4[idx];
                sv[j] = v;
                mx = fmaxf(mx, fmaxf(fmaxf(v.x, v.y), fmaxf(v.z, v.w)));
            }
        }
        #pragma unroll
        for (int m = 32; m >= 1; m >>= 1) mx = fmaxf(mx, __shfl_xor(mx, m, 64));
        if (lane == 0) r1[wv] = mx;
        __syncthreads();
        mx = fmaxf(fmaxf(r1[0], r1[1]), fmaxf(r1[2], r1[3]));
        __syncthreads();
        const float4* kr = (const float4*)(kin + ((size_t)b * HID + i) * Ssz);
        float se = 0.f, wsum = 0.f;
        #pragma unroll
        for (int j = 0; j < 4; ++j) {
            if (act[j]) {
                int idx = tid + 256 * j;
                float4 v = sv[j];
                float ex = expf(v.x - mx), ey = expf(v.y - mx);
                float ez = expf(v.z - mx), ew = expf(v.w - mx);
                se += ex + ey + ez + ew;
                float4 k4 = kr[idx];
                wsum += ex * k4.x + ey * k4.y + ez * k4.z + ew * k4.w;
            }
        }
        #pragma unroll
        for (int m = 32; m >= 1; m >>= 1) {
            se += __shfl_xor(se, m, 64);
            wsum += __shfl_xor(wsum, m, 64);
        }
        if (lane == 0) { r1[wv] = se; r2[wv] = wsum; }
        __syncthreads();
        if (tid == 0) {
            float seT = r1[0] + r1[1] + r1[2] + r1[3];
            float wsT = r2[0] + r2[1] + r2[2] + r2[3];
            ws[OFF_KBAR + b * HID + i] = wsT / seT;
        }
    }

    gbar(cnt, 6);   // KBAR ready

    // ================= phase G: apa-out (2) + corr-final (2) ================
    if (bid < 2) {
        int b = bid;
        float4* kbs = (float4*)smem;             // 64 float4
        float*  o1s = (float*)(smem + 1024);     // 256
        if (tid < 64) kbs[tid] = ((const float4*)(ws + OFF_KBAR + b * HID))[tid];
        __syncthreads();
        float4 kb4 = kbs[lane];
        const float4* wk4 = (const float4*)w_k;
        #pragma unroll 8
        for (int r = 0; r < 64; ++r) {
            int h = wv * 64 + r;
            float4 f = wk4[(size_t)h * 64 + lane];
            float p = f.x * kb4.x + f.y * kb4.y + f.z * kb4.z + f.w * kb4.w;
            #pragma unroll
            for (int m = 32; m >= 1; m >>= 1) p += __shfl_xor(p, m, 64);
            if (lane == 0) o1s[h] = p;
        }
        __syncthreads();
        float a = 0.f;
        #pragma unroll 4
        for (int d = 0; d < HID; ++d) a += o1s[d] * w_proj[(size_t)d * HID + tid];
        out[9578 + b * HID + tid] = a + b_proj[tid] + proto[b * HID + tid];
    } else if (bid < 4) {
        int b = bid - 2;
        float* sF = (float*)smem;                // 3600 floats
        float wq3 = weight[b] * (1.f / 3.f);
        const float* n0 = ws + OFF_NORM + (size_t)(b * 3) * Ssz;
        #pragma unroll
        for (int j = 0; j < 15; ++j) {
            int q = tid + j * 256;
            if (q < Ssz) {
                float s = n0[q] + n0[Ssz + q] + n0[2 * Ssz + q];
                sF[q] = s;
                out[b * Ssz + q] = wq3 * s;
            }
        }
        __syncthreads();
        #pragma unroll
        for (int j = 0; j < 5; ++j) {
            int o = tid + j * 256;
            if (o >= 1189) continue;
            int O, p, outi;
            if (o < 900)       { O = 30; p = o;        outi = 7200 + b * 900 + p; }
            else if (o < 1125) { O = 15; p = o - 900;  outi = 9000 + b * 225 + p; }
            else               { O = 8;  p = o - 1125; outi = 9450 + b * 64 + p; }
            int y = p / O, x = p - y * O;
            float sc = 59.f / (float)(O - 1);
            float py = y * sc, px = x * sc;
            int y0 = (int)floorf(py), x0 = (int)floorf(px);
            int y1 = min(y0 + 1, 59), x1 = min(x0 + 1, 59);
            float wy = py - y0, wx = px - x0;
            float v = sF[y0 * 60 + x0] * (1.f - wy) * (1.f - wx)
                    + sF[y1 * 60 + x0] * wy * (1.f - wx)
                    + sF[y0 * 60 + x1] * (1.f - wy) * wx
                    + sF[y1 * 60 + x1] * wy * wx;
            out[outi] = wq3 * v;
        }
    }
}

extern "C" void kernel_launch(void* const* d_in, const int* in_sizes, int n_in,
                              void* d_out, int out_size, void* d_ws, size_t ws_size,
                              hipStream_t stream) {
    const float* weight = (const float*)d_in[0];
    const float* query  = (const float*)d_in[1];
    const float* supp   = (const float*)d_in[2];
    const float* masks  = (const float*)d_in[3];
    const float* kin    = (const float*)d_in[4];
    const float* text   = (const float*)d_in[5];
    const float* proto  = (const float*)d_in[6];
    const float* w_q    = (const float*)d_in[7];
    const float* w_k    = (const float*)d_in[8];
    const float* w_bl   = (const float*)d_in[9];
    const float* w_proj = (const float*)d_in[10];
    const float* b_proj = (const float*)d_in[11];
    float* out = (float*)d_out;
    float* ws  = (float*)d_ws;

    // zero atomic planes + barrier counter (stream-ordered before kernel)
    hipMemsetAsync(ws, 0, (size_t)(OFF_CNT + 16) * sizeof(float), stream);

    k_mega<<<dim3(NBLK), dim3(256), 0, stream>>>(
        weight, query, supp, masks, kin, text, proto,
        w_q, w_k, w_bl, w_proj, b_proj, ws, out);
}

// Round 5
// 273.284 us; speedup vs baseline: 3.3961x; 1.7386x over previous
//
#include <hip/hip_runtime.h>
#include <math.h>

#define EPSF 1e-7f
#define Bsz 2
#define Cch 1024
#define Hh 60
#define Ssz 3600
#define HID 256
#define TDIM 300
#define MH 473

// pool tiling
#define TROWS 15
#define LROWS 21          // TROWS + 6 halo
#define LPITCH 68         // 4-col zero pad both sides of 60 cols
#define CPG 8             // channels per block (processed as 4 float2 pairs)

// workspace layout (float offsets)
// [0, 43200) zeroed by hipMemsetAsync each launch (SN2 + DOT atomic planes)
#define OFF_SN2    0               // 6*3600 sum over channels of pool^2 (atomic)
#define OFF_DOT    21600           // 6*3600 dot planes (atomic)
#define OFF_WMAP   43200           // 6*3600  mask-premultiplied pool(1/sn)
#define OFF_V      64800           // 6*1024
#define OFF_SCORE  70944           // 2*3600
#define OFF_KBAR   78144           // 2*256
#define OFF_U      78656           // 2*256

// ============ k1: pool^2 -> SN2 (1024 blocks) + u-GEMV chain (2) ============
__global__ void __launch_bounds__(256)
k_pool_u(const float* __restrict__ supp, const float* __restrict__ masks,
         const float* __restrict__ text, const float* __restrict__ proto,
         const float* __restrict__ w_q,  const float* __restrict__ w_bl,
         const float* __restrict__ w_k,  float* __restrict__ ws) {
    __shared__ __align__(16) char smem[39984];
    int tid = threadIdx.x;
    int bid = blockIdx.x;

    if (bid >= 1024) {
        // ---- u role: u = w_k^T (w_bl^T (w_q^T [text;proto])) ----
        int b = bid - 1024;
        float* xs  = (float*)smem;           // 556
        float* qxs = (float*)(smem + 2240);  // 256
        float* qws = (float*)(smem + 3264);  // 256
        #pragma unroll
        for (int j = 0; j < 3; ++j) {
            int e = tid + 256 * j;
            if (e < TDIM) xs[e] = text[b * TDIM + e];
            else if (e < TDIM + HID) xs[e] = proto[b * HID + e - TDIM];
        }
        __syncthreads();
        float a = 0.f;
        #pragma unroll 4
        for (int e = 0; e < TDIM + HID; ++e) a += xs[e] * w_q[(size_t)e * HID + tid];
        qxs[tid] = a;
        __syncthreads();
        a = 0.f;
        #pragma unroll 4
        for (int e = 0; e < HID; ++e) a += qxs[e] * w_bl[(size_t)e * HID + tid];
        qws[tid] = a;
        __syncthreads();
        a = 0.f;
        #pragma unroll 4
        for (int e = 0; e < HID; ++e) a += qws[e] * w_k[(size_t)e * HID + tid];
        ws[OFF_U + b * HID + tid] = a;
        return;
    }

    // ---- pool role ----
    float*  mk  = (float*) smem;             // 1428 floats
    float2* raw = (float2*)(smem + 5712);    // 1428 float2
    float2* h5s = (float2*)(smem + 17136);
    float2* h7s = (float2*)(smem + 28560);

    int tile = bid & 3, cgi = (bid >> 2) & 127, b = bid >> 9;
    int y0 = tile * TROWS;

    const float2 z2 = {0.f, 0.f};
    for (int i = tid; i < LROWS * LPITCH; i += 256) {
        mk[i] = 0.f; raw[i] = z2; h5s[i] = z2; h7s[i] = z2;
    }
    __syncthreads();

    int lr[5], lx[5]; bool lv[5], la[5];
    #pragma unroll
    for (int j = 0; j < 5; ++j) {
        int idx = tid + 256 * j;
        int r = idx / 60, x = idx - 60 * r;
        lr[j] = r; lx[j] = x;
        la[j] = idx < 1260;
        int iy = y0 - 3 + r;
        lv[j] = la[j] && (iy >= 0) && (iy < Hh);
    }
    #pragma unroll
    for (int j = 0; j < 5; ++j)
        if (lv[j]) {
            int iy = y0 - 3 + lr[j];
            mk[lr[j] * LPITCH + 4 + lx[j]] =
                masks[(size_t)b * MH * MH + (size_t)(iy * 8) * MH + lx[j] * 8];
        }

    int orow[4], ox[4]; bool ov[4];
    #pragma unroll
    for (int j = 0; j < 4; ++j) {
        int o = tid + 256 * j;
        int oy = o / 60, x = o - 60 * oy;
        orow[j] = oy + 3; ox[j] = x; ov[j] = o < 900;
    }
    float a0[4] = {0,0,0,0}, a1[4] = {0,0,0,0}, a2[4] = {0,0,0,0};

    const float* chbase = supp + ((size_t)b * Cch + (size_t)cgi * CPG) * Ssz + (y0 - 3) * 60;
    float pf0[5], pf1[5];
    #pragma unroll
    for (int j = 0; j < 5; ++j) {
        pf0[j] = lv[j] ? chbase[tid + 256 * j] : 0.f;
        pf1[j] = lv[j] ? chbase[Ssz + tid + 256 * j] : 0.f;
    }

    for (int p = 0; p < CPG / 2; ++p) {
        __syncthreads();
        #pragma unroll
        for (int j = 0; j < 5; ++j)
            if (lv[j]) {
                float m = mk[lr[j] * LPITCH + 4 + lx[j]];
                raw[lr[j] * LPITCH + 4 + lx[j]] = make_float2(pf0[j] * m, pf1[j] * m);
            }
        __syncthreads();
        #pragma unroll
        for (int j = 0; j < 5; ++j)
            if (la[j]) {
                int base = lr[j] * LPITCH + 4 + lx[j];
                float2 m3 = raw[base - 3], m2 = raw[base - 2], m1 = raw[base - 1];
                float2 c0 = raw[base], p1 = raw[base + 1], p2 = raw[base + 2], p3 = raw[base + 3];
                float2 h5, h7;
                h5.x = m2.x + m1.x + c0.x + p1.x + p2.x;
                h5.y = m2.y + m1.y + c0.y + p1.y + p2.y;
                h7.x = h5.x + m3.x + p3.x;
                h7.y = h5.y + m3.y + p3.y;
                h5s[base] = h5; h7s[base] = h7;
            }
        __syncthreads();
        if (p + 1 < CPG / 2) {
            const float* nb = chbase + (size_t)(2 * p + 2) * Ssz;
            #pragma unroll
            for (int j = 0; j < 5; ++j) {
                pf0[j] = lv[j] ? nb[tid + 256 * j] : 0.f;
                pf1[j] = lv[j] ? nb[Ssz + tid + 256 * j] : 0.f;
            }
        }
        #pragma unroll
        for (int j = 0; j < 4; ++j)
            if (ov[j]) {
                int base = orow[j] * LPITCH + 4 + ox[j];
                float2 sa = h5s[base - 2*LPITCH], sb = h5s[base - LPITCH], sc0 = h5s[base];
                float2 sd = h5s[base + LPITCH], se = h5s[base + 2*LPITCH];
                float p55x = (sa.x + sb.x + sc0.x + sd.x + se.x) * (1.f / 25.f);
                float p55y = (sa.y + sb.y + sc0.y + sd.y + se.y) * (1.f / 25.f);
                float2 ra = raw[base - 3*LPITCH], rb = raw[base - 2*LPITCH], rc = raw[base - LPITCH];
                float2 rd = raw[base], re = raw[base + LPITCH], rf = raw[base + 2*LPITCH], rg = raw[base + 3*LPITCH];
                float p71x = (ra.x + rb.x + rc.x + rd.x + re.x + rf.x + rg.x) * (1.f / 7.f);
                float p71y = (ra.y + rb.y + rc.y + rd.y + re.y + rf.y + rg.y) * (1.f / 7.f);
                float2 h7v = h7s[base];
                float p17x = h7v.x * (1.f / 7.f), p17y = h7v.y * (1.f / 7.f);
                a0[j] += p55x * p55x + p55y * p55y;
                a1[j] += p71x * p71x + p71y * p71y;
                a2[j] += p17x * p17x + p17y * p17y;
            }
    }
    float* acc = ws + OFF_SN2 + (size_t)(b * 3) * Ssz;
    #pragma unroll
    for (int j = 0; j < 4; ++j)
        if (ov[j]) {
            int q = (y0 + orow[j] - 3) * 60 + ox[j];
            atomicAdd(&acc[q], a0[j]);
            atomicAdd(&acc[Ssz + q], a1[j]);
            atomicAdd(&acc[2 * Ssz + q], a2[j]);
        }
}

// ============ k2: wmap (24 blocks) + score strips (58 blocks) ===============
__global__ void __launch_bounds__(1024)
k_wmap_score(const float* __restrict__ masks, const float* __restrict__ kin,
             float* __restrict__ ws) {
    int bid = blockIdx.x;
    int tid = threadIdx.x;

    if (bid < 24) {
        // ---- wmap role ----
        __shared__ float inv[LROWS * LPITCH];
        int tile = bid & 3, bk = bid >> 2;
        int b = bk / 3, kt = bk % 3;
        int y0 = tile * TROWS;
        for (int i = tid; i < LROWS * LPITCH; i += 1024) inv[i] = 0.f;
        __syncthreads();
        const float* pp = ws + OFF_SN2 + (size_t)bk * Ssz;
        #pragma unroll
        for (int j = 0; j < 2; ++j) {
            int idx = tid + 1024 * j;
            if (idx < 1260) {
                int r = idx / 60, x = idx - 60 * r;
                int iy = y0 - 3 + r;
                if (iy >= 0 && iy < Hh)
                    inv[r * LPITCH + 4 + x] = 1.0f / sqrtf(fmaxf(pp[iy * 60 + x], 1e-30f));
            }
        }
        __syncthreads();
        int kh = (kt == 0) ? 5 : (kt == 1) ? 7 : 1;
        int kw = (kt == 0) ? 5 : (kt == 2) ? 7 : 1;
        int rh = kh / 2, rw = kw / 2;
        float norm = 1.f / (float)(kh * kw);
        int o = tid;
        if (o < 900) {
            int oy = o / 60, x = o - 60 * oy;
            int base = (oy + 3) * LPITCH + 4 + x;
            float s = 0.f;
            for (int dy = -rh; dy <= rh; ++dy)
                for (int dx = -rw; dx <= rw; ++dx)
                    s += inv[base + dy * LPITCH + dx];
            int gy = y0 + oy;
            float m = masks[(size_t)b * MH * MH + (size_t)(gy * 8) * MH + x * 8];
            ws[OFF_WMAP + (size_t)bk * Ssz + gy * 60 + x] = s * norm * m;
        }
        return;
    }

    // ---- score role: 128 s-values, 8-way i-split, LDS reduce ----
    __shared__ float us[HID];
    __shared__ float part[8][128];
    int idx = bid - 24;            // 0..57
    int st = idx % 29, b = idx / 29;
    if (tid < HID) us[tid] = ws[OFF_U + b * HID + tid];
    __syncthreads();
    int sl = tid & 127, pt = tid >> 7;          // pt = 0..7
    int s = st * 128 + sl;
    float a = 0.f;
    if (s < Ssz) {
        const float* kb = kin + ((size_t)b * HID + pt * 32) * Ssz + s;
        const float* up = us + pt * 32;
        #pragma unroll
        for (int i = 0; i < 32; ++i) a += up[i] * kb[(size_t)i * Ssz];
    }
    part[pt][sl] = a;
    __syncthreads();
    if (tid < 128 && st * 128 + tid < Ssz) {
        float t = 0.f;
        #pragma unroll
        for (int p = 0; p < 8; ++p) t += part[p][tid];
        ws[OFF_SCORE + (size_t)b * Ssz + st * 128 + tid] = t;
    }
}

// ============ k3: v (512 blocks) + kbar (512 blocks) ========================
__global__ void __launch_bounds__(256)
k_v_kbar(const float* __restrict__ supp, const float* __restrict__ kin,
         float* __restrict__ ws) {
    int bid = blockIdx.x;
    int tid = threadIdx.x, lane = tid & 63, w = tid >> 6;

    if (bid < 512) {
        // ---- v role ----
        int cB = bid & 255, b = bid >> 8;
        int c0 = cB * 4;
        const float4* sp4 = (const float4*)(supp + ((size_t)b * Cch + c0) * Ssz);
        const float4* w04 = (const float4*)(ws + OFF_WMAP + (size_t)(b * 3 + 0) * Ssz);
        const float4* w14 = (const float4*)(ws + OFF_WMAP + (size_t)(b * 3 + 1) * Ssz);
        const float4* w24 = (const float4*)(ws + OFF_WMAP + (size_t)(b * 3 + 2) * Ssz);
        float a[4][3];
        #pragma unroll
        for (int cc = 0; cc < 4; ++cc) { a[cc][0] = 0; a[cc][1] = 0; a[cc][2] = 0; }
        #pragma unroll
        for (int j = 0; j < 4; ++j) {
            int idx = tid + 256 * j;
            if (idx < 900) {
                float4 g0 = w04[idx], g1 = w14[idx], g2 = w24[idx];
                #pragma unroll
                for (int cc = 0; cc < 4; ++cc) {
                    float4 f = sp4[cc * 900 + idx];
                    a[cc][0] += f.x * g0.x + f.y * g0.y + f.z * g0.z + f.w * g0.w;
                    a[cc][1] += f.x * g1.x + f.y * g1.y + f.z * g1.z + f.w * g1.w;
                    a[cc][2] += f.x * g2.x + f.y * g2.y + f.z * g2.z + f.w * g2.w;
                }
            }
        }
        #pragma unroll
        for (int m = 32; m >= 1; m >>= 1)
            #pragma unroll
            for (int cc = 0; cc < 4; ++cc) {
                a[cc][0] += __shfl_xor(a[cc][0], m, 64);
                a[cc][1] += __shfl_xor(a[cc][1], m, 64);
                a[cc][2] += __shfl_xor(a[cc][2], m, 64);
            }
        __shared__ float r[4][3][4];
        if (lane == 0)
            #pragma unroll
            for (int cc = 0; cc < 4; ++cc) {
                r[cc][0][w] = a[cc][0]; r[cc][1][w] = a[cc][1]; r[cc][2][w] = a[cc][2];
            }
        __syncthreads();
        if (tid < 12) {
            int cc = tid / 3, kk = tid - cc * 3;
            float s = r[cc][kk][0] + r[cc][kk][1] + r[cc][kk][2] + r[cc][kk][3];
            ws[OFF_V + (size_t)(b * 3 + kk) * Cch + c0 + cc] = s;
        }
        return;
    }

    // ---- kbar role ----
    int u2 = bid - 512;
    int i = u2 & 255, b = u2 >> 8;
    __shared__ float r1[4], r2[4];
    const float4* s4 = (const float4*)(ws + OFF_SCORE + (size_t)b * Ssz);
    float4 sv[4]; bool act[4];
    float mx = -INFINITY;
    #pragma unroll
    for (int j = 0; j < 4; ++j) {
        int idx = tid + 256 * j;
        act[j] = idx < 900;
        if (act[j]) {
            float4 v = s4[idx];
            sv[j] = v;
            mx = fmaxf(mx, fmaxf(fmaxf(v.x, v.y), fmaxf(v.z, v.w)));
        }
    }
    #pragma unroll
    for (int m = 32; m >= 1; m >>= 1) mx = fmaxf(mx, __shfl_xor(mx, m, 64));
    if (lane == 0) r1[w] = mx;
    __syncthreads();
    mx = fmaxf(fmaxf(r1[0], r1[1]), fmaxf(r1[2], r1[3]));
    __syncthreads();
    const float4* kr = (const float4*)(kin + ((size_t)b * HID + i) * Ssz);
    float se = 0.f, wsum = 0.f;
    #pragma unroll
    for (int j = 0; j < 4; ++j) {
        if (act[j]) {
            int idx = tid + 256 * j;
            float4 v = sv[j];
            float ex = expf(v.x - mx), ey = expf(v.y - mx);
            float ez = expf(v.z - mx), ew = expf(v.w - mx);
            se += ex + ey + ez + ew;
            float4 k4 = kr[idx];
            wsum += ex * k4.x + ey * k4.y + ez * k4.z + ew * k4.w;
        }
    }
    #pragma unroll
    for (int m = 32; m >= 1; m >>= 1) {
        se += __shfl_xor(se, m, 64);
        wsum += __shfl_xor(wsum, m, 64);
    }
    if (lane == 0) { r1[w] = se; r2[w] = wsum; }
    __syncthreads();
    if (tid == 0) {
        float seT = r1[0] + r1[1] + r1[2] + r1[3];
        float wsT = r2[0] + r2[1] + r2[2] + r2[3];
        ws[OFF_KBAR + b * HID + i] = wsT / seT;
    }
}

// ============ k4: dot planes (480 blocks) + apa-out (2 blocks) ==============
__global__ void __launch_bounds__(256)
k_dot_apa(const float* __restrict__ query, const float* __restrict__ w_k,
          const float* __restrict__ w_proj, const float* __restrict__ b_proj,
          const float* __restrict__ proto, float* __restrict__ ws,
          float* __restrict__ out) {
    int bid = blockIdx.x;
    int tid = threadIdx.x, lane = tid & 63, wv = tid >> 6;

    if (bid < 480) {
        int qt = bid % 15, cc = (bid / 15) & 15, b = bid / 240;
        int q = qt * 256 + tid;
        if (q < Ssz) {
            const float* v0 = ws + OFF_V + (size_t)(b * 3 + 0) * Cch;
            const float* v1 = ws + OFF_V + (size_t)(b * 3 + 1) * Cch;
            const float* v2 = ws + OFF_V + (size_t)(b * 3 + 2) * Cch;
            float a0 = 0, a1 = 0, a2 = 0;
            int c0 = cc * 64;
            #pragma unroll 8
            for (int c = c0; c < c0 + 64; ++c) {
                float qv = query[((size_t)b * Cch + c) * Ssz + q];
                a0 += qv * v0[c]; a1 += qv * v1[c]; a2 += qv * v2[c];
            }
            float* dst = ws + OFF_DOT + (size_t)(b * 3) * Ssz + q;
            atomicAdd(&dst[0], a0);
            atomicAdd(&dst[Ssz], a1);
            atomicAdd(&dst[2 * Ssz], a2);
        }
        return;
    }

    // ---- apa-out role ----
    int b = bid - 480;
    __shared__ float4 kbs[64];
    __shared__ float o1s[256];
    if (tid < 64) kbs[tid] = ((const float4*)(ws + OFF_KBAR + b * HID))[tid];
    __syncthreads();
    float4 kb4 = kbs[lane];
    const float4* wk4 = (const float4*)w_k;
    #pragma unroll 8
    for (int r = 0; r < 64; ++r) {
        int h = wv * 64 + r;
        float4 f = wk4[(size_t)h * 64 + lane];
        float p = f.x * kb4.x + f.y * kb4.y + f.z * kb4.z + f.w * kb4.w;
        #pragma unroll
        for (int m = 32; m >= 1; m >>= 1) p += __shfl_xor(p, m, 64);
        if (lane == 0) o1s[h] = p;
    }
    __syncthreads();
    float a = 0.f;
    #pragma unroll 4
    for (int d = 0; d < HID; ++d) a += o1s[d] * w_proj[(size_t)d * HID + tid];
    out[9578 + b * HID + tid] = a + b_proj[tid] + proto[b * HID + tid];
}

// ============ k5: sim x3 planes fused with corr-final (2 blocks) ============
__global__ void __launch_bounds__(1024)
k_simcorr(const float* __restrict__ weight, float* __restrict__ ws,
          float* __restrict__ out) {
    __shared__ float sA[66 * LPITCH];
    __shared__ float sB[66 * LPITCH];
    __shared__ float sF[Ssz];
    __shared__ float rmn[16], rmx[16];
    int b = blockIdx.x;
    int tid = threadIdx.x;
    int lane = tid & 63, wv = tid >> 6;

    for (int kt = 0; kt < 3; ++kt) {
        __syncthreads();   // protect sA/sB/rmn reuse across iterations
        const float* dp0 = ws + OFF_DOT + (size_t)(b * 3 + kt) * Ssz;
        for (int i = tid; i < 66 * LPITCH; i += 1024) {
            int r = i / LPITCH, col = i - r * LPITCH;
            int y = r - 3, x = col - 4;
            float s = 0.f;
            if (y >= 0 && y < Hh && x >= 0 && x < Hh) s = dp0[y * Hh + x];
            sA[i] = s;
        }
        __syncthreads();
        if (kt != 1) {
            for (int idx = tid; idx < 66 * 60; idx += 1024) {
                int r = idx / 60, x = idx - 60 * r;
                int base = r * LPITCH + 4 + x;
                if (kt == 0)
                    sB[base] = sA[base - 2] + sA[base - 1] + sA[base] + sA[base + 1] + sA[base + 2];
                else
                    sB[base] = sA[base - 3] + sA[base - 2] + sA[base - 1] + sA[base]
                             + sA[base + 1] + sA[base + 2] + sA[base + 3];
            }
        }
        __syncthreads();
        float norm = ((kt == 0) ? (1.f / 25.f) : (1.f / 7.f)) * (1.f / (float)Ssz);
        float vals[4];
        float vmin = INFINITY, vmax = -INFINITY;
        #pragma unroll
        for (int j = 0; j < 4; ++j) {
            int q = tid + j * 1024;
            if (q < Ssz) {
                int y = q / Hh, x = q - y * Hh;
                int base = (y + 3) * LPITCH + 4 + x;
                float s;
                if (kt == 0)
                    s = sB[base - 2*LPITCH] + sB[base - LPITCH] + sB[base]
                      + sB[base + LPITCH] + sB[base + 2*LPITCH];
                else if (kt == 1)
                    s = sA[base - 3*LPITCH] + sA[base - 2*LPITCH] + sA[base - LPITCH]
                      + sA[base] + sA[base + LPITCH] + sA[base + 2*LPITCH] + sA[base + 3*LPITCH];
                else
                    s = sB[base];
                float val = s * norm;
                vals[j] = val;
                vmin = fminf(vmin, val); vmax = fmaxf(vmax, val);
            }
        }
        #pragma unroll
        for (int m = 32; m >= 1; m >>= 1) {
            vmin = fminf(vmin, __shfl_xor(vmin, m, 64));
            vmax = fmaxf(vmax, __shfl_xor(vmax, m, 64));
        }
        if (lane == 0) { rmn[wv] = vmin; rmx[wv] = vmax; }
        __syncthreads();
        float mn = rmn[0], mx = rmx[0];
        #pragma unroll
        for (int ww = 1; ww < 16; ++ww) {
            mn = fminf(mn, rmn[ww]); mx = fmaxf(mx, rmx[ww]);
        }
        float inv = 1.f / (mx - mn + EPSF);
        #pragma unroll
        for (int j = 0; j < 4; ++j) {
            int q = tid + j * 1024;
            if (q < Ssz) {
                float nv = (vals[j] - mn) * inv;
                if (kt == 0) sF[q] = nv; else sF[q] += nv;
            }
        }
    }
    __syncthreads();

    // ---- corr final ----
    float wq3 = weight[b] * (1.f / 3.f);
    #pragma unroll
    for (int j = 0; j < 4; ++j) {
        int q = tid + j * 1024;
        if (q < Ssz) out[b * Ssz + q] = wq3 * sF[q];
    }
    #pragma unroll
    for (int j = 0; j < 2; ++j) {
        int o = tid + j * 1024;
        if (o >= 1189) continue;
        int O, p, outi;
        if (o < 900)       { O = 30; p = o;        outi = 7200 + b * 900 + p; }
        else if (o < 1125) { O = 15; p = o - 900;  outi = 9000 + b * 225 + p; }
        else               { O = 8;  p = o - 1125; outi = 9450 + b * 64 + p; }
        int y = p / O, x = p - y * O;
        float sc = 59.f / (float)(O - 1);
        float py = y * sc, px = x * sc;
        int y0 = (int)floorf(py), x0 = (int)floorf(px);
        int y1 = min(y0 + 1, 59), x1 = min(x0 + 1, 59);
        float wy = py - y0, wx = px - x0;
        float v = sF[y0 * 60 + x0] * (1.f - wy) * (1.f - wx)
                + sF[y1 * 60 + x0] * wy * (1.f - wx)
                + sF[y0 * 60 + x1] * (1.f - wy) * wx
                + sF[y1 * 60 + x1] * wy * wx;
        out[outi] = wq3 * v;
    }
}

extern "C" void kernel_launch(void* const* d_in, const int* in_sizes, int n_in,
                              void* d_out, int out_size, void* d_ws, size_t ws_size,
                              hipStream_t stream) {
    const float* weight = (const float*)d_in[0];
    const float* query  = (const float*)d_in[1];
    const float* supp   = (const float*)d_in[2];
    const float* masks  = (const float*)d_in[3];
    const float* kin    = (const float*)d_in[4];
    const float* text   = (const float*)d_in[5];
    const float* proto  = (const float*)d_in[6];
    const float* w_q    = (const float*)d_in[7];
    const float* w_k    = (const float*)d_in[8];
    const float* w_bl   = (const float*)d_in[9];
    const float* w_proj = (const float*)d_in[10];
    const float* b_proj = (const float*)d_in[11];
    float* out = (float*)d_out;
    float* ws  = (float*)d_ws;

    // zero atomic accumulator planes (SN2 + DOT)
    hipMemsetAsync(ws, 0, (size_t)OFF_WMAP * sizeof(float), stream);

    k_pool_u<<<1026, 256, 0, stream>>>(supp, masks, text, proto, w_q, w_bl, w_k, ws);
    k_wmap_score<<<82, 1024, 0, stream>>>(masks, kin, ws);
    k_v_kbar<<<1024, 256, 0, stream>>>(supp, kin, ws);
    k_dot_apa<<<482, 256, 0, stream>>>(query, w_k, w_proj, b_proj, proto, ws, out);
    k_simcorr<<<Bsz, 1024, 0, stream>>>(weight, ws, out);
}

// Round 6
// 249.758 us; speedup vs baseline: 3.7160x; 1.0942x over previous
//
#include <hip/hip_runtime.h>
#include <math.h>

#define EPSF 1e-7f
#define Bsz 2
#define Cch 1024
#define Hh 60
#define Ssz 3600
#define HID 256
#define TDIM 300
#define MH 473

// pool tiling
#define TROWS 15
#define LROWS 21          // TROWS + 6 halo
#define LPITCH 68         // 4-col zero pad both sides of 60 cols
#define CPG 8             // channels per block (processed as 4 float2 pairs)

// workspace layout (float offsets)
// [0, 43200) zeroed by hipMemsetAsync each launch (SN2 + DOT atomic planes)
#define OFF_SN2    0               // 6*3600 sum over channels of pool^2 (atomic)
#define OFF_DOT    21600           // 6*3600 dot planes (atomic)
#define OFF_WMAP   43200           // 6*3600  mask-premultiplied pool(1/sn)
#define OFF_V      64800           // 6*1024
#define OFF_SCORE  70944           // 2*3600
#define OFF_KBAR   78144           // 2*256
#define OFF_U      78656           // 2*256

// ============ k1: pool^2 -> SN2 (1024 blocks) + u-GEMV chain (2) ============
// LDS: mk 5712B | raw 11424B | h5s 11424B = 28560B (h7 computed inline)
__global__ void __launch_bounds__(256)
k_pool_u(const float* __restrict__ supp, const float* __restrict__ masks,
         const float* __restrict__ text, const float* __restrict__ proto,
         const float* __restrict__ w_q,  const float* __restrict__ w_bl,
         const float* __restrict__ w_k,  float* __restrict__ ws) {
    __shared__ __align__(16) char smem[28560];
    int tid = threadIdx.x;
    int bid = blockIdx.x;

    if (bid >= 1024) {
        // ---- u role: u = w_k^T (w_bl^T (w_q^T [text;proto])), 4-wave float4 ----
        int b = bid - 1024;
        int lane = tid & 63, wv = tid >> 6;
        float4* p4  = (float4*)smem;            // [4][64]
        float*  pf  = (float*)smem;
        float*  xs  = (float*)(smem + 4096);    // 556
        float*  qxs = (float*)(smem + 6400);    // 256
        float*  qws = (float*)(smem + 7424);    // 256
        const float4* wq4  = (const float4*)w_q;
        const float4* wbl4 = (const float4*)w_bl;
        const float4* wk4  = (const float4*)w_k;

        #pragma unroll
        for (int j = 0; j < 3; ++j) {
            int e = tid + 256 * j;
            if (e < TDIM) xs[e] = text[b * TDIM + e];
            else if (e < TDIM + HID) xs[e] = proto[b * HID + e - TDIM];
        }
        __syncthreads();
        float4 acc = {0.f, 0.f, 0.f, 0.f};
        #pragma unroll 4
        for (int j = 0; j < 139; ++j) {
            int e = wv + 4 * j;
            if (e < TDIM + HID) {
                float x = xs[e];
                float4 f = wq4[(size_t)e * 64 + lane];
                acc.x += x * f.x; acc.y += x * f.y; acc.z += x * f.z; acc.w += x * f.w;
            }
        }
        p4[wv * 64 + lane] = acc;
        __syncthreads();
        qxs[tid] = pf[tid] + pf[256 + tid] + pf[512 + tid] + pf[768 + tid];
        __syncthreads();

        acc.x = acc.y = acc.z = acc.w = 0.f;
        #pragma unroll 4
        for (int j = 0; j < 64; ++j) {
            int e = wv + 4 * j;
            float x = qxs[e];
            float4 f = wbl4[(size_t)e * 64 + lane];
            acc.x += x * f.x; acc.y += x * f.y; acc.z += x * f.z; acc.w += x * f.w;
        }
        p4[wv * 64 + lane] = acc;
        __syncthreads();
        qws[tid] = pf[tid] + pf[256 + tid] + pf[512 + tid] + pf[768 + tid];
        __syncthreads();

        acc.x = acc.y = acc.z = acc.w = 0.f;
        #pragma unroll 4
        for (int j = 0; j < 64; ++j) {
            int e = wv + 4 * j;
            float x = qws[e];
            float4 f = wk4[(size_t)e * 64 + lane];
            acc.x += x * f.x; acc.y += x * f.y; acc.z += x * f.z; acc.w += x * f.w;
        }
        p4[wv * 64 + lane] = acc;
        __syncthreads();
        ws[OFF_U + b * HID + tid] = pf[tid] + pf[256 + tid] + pf[512 + tid] + pf[768 + tid];
        return;
    }

    // ---- pool role ----
    float*  mk  = (float*) smem;             // 1428 floats
    float2* raw = (float2*)(smem + 5712);    // 1428 float2
    float2* h5s = (float2*)(smem + 17136);   // 1428 float2

    int tile = bid & 3, cgi = (bid >> 2) & 127, b = bid >> 9;
    int y0 = tile * TROWS;

    const float2 z2 = {0.f, 0.f};
    for (int i = tid; i < LROWS * LPITCH; i += 256) {
        mk[i] = 0.f; raw[i] = z2; h5s[i] = z2;
    }
    __syncthreads();

    int lr[5], lx[5]; bool lv[5], la[5];
    #pragma unroll
    for (int j = 0; j < 5; ++j) {
        int idx = tid + 256 * j;
        int r = idx / 60, x = idx - 60 * r;
        lr[j] = r; lx[j] = x;
        la[j] = idx < 1260;
        int iy = y0 - 3 + r;
        lv[j] = la[j] && (iy >= 0) && (iy < Hh);
    }
    #pragma unroll
    for (int j = 0; j < 5; ++j)
        if (lv[j]) {
            int iy = y0 - 3 + lr[j];
            mk[lr[j] * LPITCH + 4 + lx[j]] =
                masks[(size_t)b * MH * MH + (size_t)(iy * 8) * MH + lx[j] * 8];
        }

    int orow[4], ox[4]; bool ov[4];
    #pragma unroll
    for (int j = 0; j < 4; ++j) {
        int o = tid + 256 * j;
        int oy = o / 60, x = o - 60 * oy;
        orow[j] = oy + 3; ox[j] = x; ov[j] = o < 900;
    }
    float a0[4] = {0,0,0,0}, a1[4] = {0,0,0,0}, a2[4] = {0,0,0,0};

    const float* chbase = supp + ((size_t)b * Cch + (size_t)cgi * CPG) * Ssz + (y0 - 3) * 60;
    float pf0[5], pf1[5];
    #pragma unroll
    for (int j = 0; j < 5; ++j) {
        pf0[j] = lv[j] ? chbase[tid + 256 * j] : 0.f;
        pf1[j] = lv[j] ? chbase[Ssz + tid + 256 * j] : 0.f;
    }

    for (int p = 0; p < CPG / 2; ++p) {
        __syncthreads();
        #pragma unroll
        for (int j = 0; j < 5; ++j)
            if (lv[j]) {
                float m = mk[lr[j] * LPITCH + 4 + lx[j]];
                raw[lr[j] * LPITCH + 4 + lx[j]] = make_float2(pf0[j] * m, pf1[j] * m);
            }
        __syncthreads();
        #pragma unroll
        for (int j = 0; j < 5; ++j)
            if (la[j]) {
                int base = lr[j] * LPITCH + 4 + lx[j];
                float2 m2 = raw[base - 2], m1 = raw[base - 1];
                float2 c0 = raw[base], p1 = raw[base + 1], p2 = raw[base + 2];
                float2 h5;
                h5.x = m2.x + m1.x + c0.x + p1.x + p2.x;
                h5.y = m2.y + m1.y + c0.y + p1.y + p2.y;
                h5s[base] = h5;
            }
        __syncthreads();
        if (p + 1 < CPG / 2) {
            const float* nb = chbase + (size_t)(2 * p + 2) * Ssz;
            #pragma unroll
            for (int j = 0; j < 5; ++j) {
                pf0[j] = lv[j] ? nb[tid + 256 * j] : 0.f;
                pf1[j] = lv[j] ? nb[Ssz + tid + 256 * j] : 0.f;
            }
        }
        #pragma unroll
        for (int j = 0; j < 4; ++j)
            if (ov[j]) {
                int base = orow[j] * LPITCH + 4 + ox[j];
                float2 sa = h5s[base - 2*LPITCH], sb = h5s[base - LPITCH], sc0 = h5s[base];
                float2 sd = h5s[base + LPITCH], se = h5s[base + 2*LPITCH];
                float p55x = (sa.x + sb.x + sc0.x + sd.x + se.x) * (1.f / 25.f);
                float p55y = (sa.y + sb.y + sc0.y + sd.y + se.y) * (1.f / 25.f);
                float2 ra = raw[base - 3*LPITCH], rb = raw[base - 2*LPITCH], rc = raw[base - LPITCH];
                float2 rd = raw[base], re = raw[base + LPITCH], rf = raw[base + 2*LPITCH], rg = raw[base + 3*LPITCH];
                float p71x = (ra.x + rb.x + rc.x + rd.x + re.x + rf.x + rg.x) * (1.f / 7.f);
                float p71y = (ra.y + rb.y + rc.y + rd.y + re.y + rf.y + rg.y) * (1.f / 7.f);
                float2 m3o = raw[base - 3], p3o = raw[base + 3];    // h7 inline
                float p17x = (sc0.x + m3o.x + p3o.x) * (1.f / 7.f);
                float p17y = (sc0.y + m3o.y + p3o.y) * (1.f / 7.f);
                a0[j] += p55x * p55x + p55y * p55y;
                a1[j] += p71x * p71x + p71y * p71y;
                a2[j] += p17x * p17x + p17y * p17y;
            }
    }
    float* acc = ws + OFF_SN2 + (size_t)(b * 3) * Ssz;
    #pragma unroll
    for (int j = 0; j < 4; ++j)
        if (ov[j]) {
            int q = (y0 + orow[j] - 3) * 60 + ox[j];
            atomicAdd(&acc[q], a0[j]);
            atomicAdd(&acc[Ssz + q], a1[j]);
            atomicAdd(&acc[2 * Ssz + q], a2[j]);
        }
}

// ============ k2: wmap (24 blocks) + score strips (58 blocks) ===============
__global__ void __launch_bounds__(1024)
k_wmap_score(const float* __restrict__ masks, const float* __restrict__ kin,
             float* __restrict__ ws) {
    int bid = blockIdx.x;
    int tid = threadIdx.x;

    if (bid < 24) {
        // ---- wmap role ----
        __shared__ float inv[LROWS * LPITCH];
        int tile = bid & 3, bk = bid >> 2;
        int b = bk / 3, kt = bk % 3;
        int y0 = tile * TROWS;
        for (int i = tid; i < LROWS * LPITCH; i += 1024) inv[i] = 0.f;
        __syncthreads();
        const float* pp = ws + OFF_SN2 + (size_t)bk * Ssz;
        #pragma unroll
        for (int j = 0; j < 2; ++j) {
            int idx = tid + 1024 * j;
            if (idx < 1260) {
                int r = idx / 60, x = idx - 60 * r;
                int iy = y0 - 3 + r;
                if (iy >= 0 && iy < Hh)
                    inv[r * LPITCH + 4 + x] = 1.0f / sqrtf(fmaxf(pp[iy * 60 + x], 1e-30f));
            }
        }
        __syncthreads();
        int kh = (kt == 0) ? 5 : (kt == 1) ? 7 : 1;
        int kw = (kt == 0) ? 5 : (kt == 2) ? 7 : 1;
        int rh = kh / 2, rw = kw / 2;
        float norm = 1.f / (float)(kh * kw);
        int o = tid;
        if (o < 900) {
            int oy = o / 60, x = o - 60 * oy;
            int base = (oy + 3) * LPITCH + 4 + x;
            float s = 0.f;
            for (int dy = -rh; dy <= rh; ++dy)
                for (int dx = -rw; dx <= rw; ++dx)
                    s += inv[base + dy * LPITCH + dx];
            int gy = y0 + oy;
            float m = masks[(size_t)b * MH * MH + (size_t)(gy * 8) * MH + x * 8];
            ws[OFF_WMAP + (size_t)bk * Ssz + gy * 60 + x] = s * norm * m;
        }
        return;
    }

    // ---- score role: 128 s-values, 8-way i-split, LDS reduce ----
    __shared__ float us[HID];
    __shared__ float part[8][128];
    int idx = bid - 24;            // 0..57
    int st = idx % 29, b = idx / 29;
    if (tid < HID) us[tid] = ws[OFF_U + b * HID + tid];
    __syncthreads();
    int sl = tid & 127, pt = tid >> 7;          // pt = 0..7
    int s = st * 128 + sl;
    float a = 0.f;
    if (s < Ssz) {
        const float* kb = kin + ((size_t)b * HID + pt * 32) * Ssz + s;
        const float* up = us + pt * 32;
        #pragma unroll
        for (int i = 0; i < 32; ++i) a += up[i] * kb[(size_t)i * Ssz];
    }
    part[pt][sl] = a;
    __syncthreads();
    if (tid < 128 && st * 128 + tid < Ssz) {
        float t = 0.f;
        #pragma unroll
        for (int p = 0; p < 8; ++p) t += part[p][tid];
        ws[OFF_SCORE + (size_t)b * Ssz + st * 128 + tid] = t;
    }
}

// ============ k3: v (512 blocks) + kbar (512 blocks) ========================
__global__ void __launch_bounds__(256)
k_v_kbar(const float* __restrict__ supp, const float* __restrict__ kin,
         float* __restrict__ ws) {
    int bid = blockIdx.x;
    int tid = threadIdx.x, lane = tid & 63, w = tid >> 6;

    if (bid < 512) {
        // ---- v role ----
        int cB = bid & 255, b = bid >> 8;
        int c0 = cB * 4;
        const float4* sp4 = (const float4*)(supp + ((size_t)b * Cch + c0) * Ssz);
        const float4* w04 = (const float4*)(ws + OFF_WMAP + (size_t)(b * 3 + 0) * Ssz);
        const float4* w14 = (const float4*)(ws + OFF_WMAP + (size_t)(b * 3 + 1) * Ssz);
        const float4* w24 = (const float4*)(ws + OFF_WMAP + (size_t)(b * 3 + 2) * Ssz);
        float a[4][3];
        #pragma unroll
        for (int cc = 0; cc < 4; ++cc) { a[cc][0] = 0; a[cc][1] = 0; a[cc][2] = 0; }
        #pragma unroll
        for (int j = 0; j < 4; ++j) {
            int idx = tid + 256 * j;
            if (idx < 900) {
                float4 g0 = w04[idx], g1 = w14[idx], g2 = w24[idx];
                #pragma unroll
                for (int cc = 0; cc < 4; ++cc) {
                    float4 f = sp4[cc * 900 + idx];
                    a[cc][0] += f.x * g0.x + f.y * g0.y + f.z * g0.z + f.w * g0.w;
                    a[cc][1] += f.x * g1.x + f.y * g1.y + f.z * g1.z + f.w * g1.w;
                    a[cc][2] += f.x * g2.x + f.y * g2.y + f.z * g2.z + f.w * g2.w;
                }
            }
        }
        #pragma unroll
        for (int m = 32; m >= 1; m >>= 1)
            #pragma unroll
            for (int cc = 0; cc < 4; ++cc) {
                a[cc][0] += __shfl_xor(a[cc][0], m, 64);
                a[cc][1] += __shfl_xor(a[cc][1], m, 64);
                a[cc][2] += __shfl_xor(a[cc][2], m, 64);
            }
        __shared__ float r[4][3][4];
        if (lane == 0)
            #pragma unroll
            for (int cc = 0; cc < 4; ++cc) {
                r[cc][0][w] = a[cc][0]; r[cc][1][w] = a[cc][1]; r[cc][2][w] = a[cc][2];
            }
        __syncthreads();
        if (tid < 12) {
            int cc = tid / 3, kk = tid - cc * 3;
            float s = r[cc][kk][0] + r[cc][kk][1] + r[cc][kk][2] + r[cc][kk][3];
            ws[OFF_V + (size_t)(b * 3 + kk) * Cch + c0 + cc] = s;
        }
        return;
    }

    // ---- kbar role ----
    int u2 = bid - 512;
    int i = u2 & 255, b = u2 >> 8;
    __shared__ float r1[4], r2[4];
    const float4* s4 = (const float4*)(ws + OFF_SCORE + (size_t)b * Ssz);
    float4 sv[4]; bool act[4];
    float mx = -INFINITY;
    #pragma unroll
    for (int j = 0; j < 4; ++j) {
        int idx = tid + 256 * j;
        act[j] = idx < 900;
        if (act[j]) {
            float4 v = s4[idx];
            sv[j] = v;
            mx = fmaxf(mx, fmaxf(fmaxf(v.x, v.y), fmaxf(v.z, v.w)));
        }
    }
    #pragma unroll
    for (int m = 32; m >= 1; m >>= 1) mx = fmaxf(mx, __shfl_xor(mx, m, 64));
    if (lane == 0) r1[w] = mx;
    __syncthreads();
    mx = fmaxf(fmaxf(r1[0], r1[1]), fmaxf(r1[2], r1[3]));
    __syncthreads();
    const float4* kr = (const float4*)(kin + ((size_t)b * HID + i) * Ssz);
    float se = 0.f, wsum = 0.f;
    #pragma unroll
    for (int j = 0; j < 4; ++j) {
        if (act[j]) {
            int idx = tid + 256 * j;
            float4 v = sv[j];
            float ex = expf(v.x - mx), ey = expf(v.y - mx);
            float ez = expf(v.z - mx), ew = expf(v.w - mx);
            se += ex + ey + ez + ew;
            float4 k4 = kr[idx];
            wsum += ex * k4.x + ey * k4.y + ez * k4.z + ew * k4.w;
        }
    }
    #pragma unroll
    for (int m = 32; m >= 1; m >>= 1) {
        se += __shfl_xor(se, m, 64);
        wsum += __shfl_xor(wsum, m, 64);
    }
    if (lane == 0) { r1[w] = se; r2[w] = wsum; }
    __syncthreads();
    if (tid == 0) {
        float seT = r1[0] + r1[1] + r1[2] + r1[3];
        float wsT = r2[0] + r2[1] + r2[2] + r2[3];
        ws[OFF_KBAR + b * HID + i] = wsT / seT;
    }
}

// ============ k4: dot planes (480 blocks) + apa-out (2 blocks) ==============
__global__ void __launch_bounds__(256)
k_dot_apa(const float* __restrict__ query, const float* __restrict__ w_k,
          const float* __restrict__ w_proj, const float* __restrict__ b_proj,
          const float* __restrict__ proto, float* __restrict__ ws,
          float* __restrict__ out) {
    int bid = blockIdx.x;
    int tid = threadIdx.x, lane = tid & 63, wv = tid >> 6;

    if (bid < 480) {
        int qt = bid % 15, cc = (bid / 15) & 15, b = bid / 240;
        int q = qt * 256 + tid;
        if (q < Ssz) {
            const float* v0 = ws + OFF_V + (size_t)(b * 3 + 0) * Cch;
            const float* v1 = ws + OFF_V + (size_t)(b * 3 + 1) * Cch;
            const float* v2 = ws + OFF_V + (size_t)(b * 3 + 2) * Cch;
            float a0 = 0, a1 = 0, a2 = 0;
            int c0 = cc * 64;
            #pragma unroll 8
            for (int c = c0; c < c0 + 64; ++c) {
                float qv = query[((size_t)b * Cch + c) * Ssz + q];
                a0 += qv * v0[c]; a1 += qv * v1[c]; a2 += qv * v2[c];
            }
            float* dst = ws + OFF_DOT + (size_t)(b * 3) * Ssz + q;
            atomicAdd(&dst[0], a0);
            atomicAdd(&dst[Ssz], a1);
            atomicAdd(&dst[2 * Ssz], a2);
        }
        return;
    }

    // ---- apa-out role ----
    int b = bid - 480;
    __shared__ float4 kbs[64];
    __shared__ float o1s[256];
    if (tid < 64) kbs[tid] = ((const float4*)(ws + OFF_KBAR + b * HID))[tid];
    __syncthreads();
    float4 kb4 = kbs[lane];
    const float4* wk4 = (const float4*)w_k;
    #pragma unroll 8
    for (int r = 0; r < 64; ++r) {
        int h = wv * 64 + r;
        float4 f = wk4[(size_t)h * 64 + lane];
        float p = f.x * kb4.x + f.y * kb4.y + f.z * kb4.z + f.w * kb4.w;
        #pragma unroll
        for (int m = 32; m >= 1; m >>= 1) p += __shfl_xor(p, m, 64);
        if (lane == 0) o1s[h] = p;
    }
    __syncthreads();
    float a = 0.f;
    #pragma unroll 4
    for (int d = 0; d < HID; ++d) a += o1s[d] * w_proj[(size_t)d * HID + tid];
    out[9578 + b * HID + tid] = a + b_proj[tid] + proto[b * HID + tid];
}

// ============ k5: sim x3 planes fused with corr-final (2 blocks) ============
__global__ void __launch_bounds__(1024)
k_simcorr(const float* __restrict__ weight, float* __restrict__ ws,
          float* __restrict__ out) {
    __shared__ float sA[66 * LPITCH];
    __shared__ float sB[66 * LPITCH];
    __shared__ float sF[Ssz];
    __shared__ float rmn[16], rmx[16];
    int b = blockIdx.x;
    int tid = threadIdx.x;
    int lane = tid & 63, wv = tid >> 6;

    for (int kt = 0; kt < 3; ++kt) {
        __syncthreads();   // protect sA/sB/rmn reuse across iterations
        const float* dp0 = ws + OFF_DOT + (size_t)(b * 3 + kt) * Ssz;
        for (int i = tid; i < 66 * LPITCH; i += 1024) {
            int r = i / LPITCH, col = i - r * LPITCH;
            int y = r - 3, x = col - 4;
            float s = 0.f;
            if (y >= 0 && y < Hh && x >= 0 && x < Hh) s = dp0[y * Hh + x];
            sA[i] = s;
        }
        __syncthreads();
        if (kt != 1) {
            for (int idx = tid; idx < 66 * 60; idx += 1024) {
                int r = idx / 60, x = idx - 60 * r;
                int base = r * LPITCH + 4 + x;
                if (kt == 0)
                    sB[base] = sA[base - 2] + sA[base - 1] + sA[base] + sA[base + 1] + sA[base + 2];
                else
                    sB[base] = sA[base - 3] + sA[base - 2] + sA[base - 1] + sA[base]
                             + sA[base + 1] + sA[base + 2] + sA[base + 3];
            }
        }
        __syncthreads();
        float norm = ((kt == 0) ? (1.f / 25.f) : (1.f / 7.f)) * (1.f / (float)Ssz);
        float vals[4];
        float vmin = INFINITY, vmax = -INFINITY;
        #pragma unroll
        for (int j = 0; j < 4; ++j) {
            int q = tid + j * 1024;
            if (q < Ssz) {
                int y = q / Hh, x = q - y * Hh;
                int base = (y + 3) * LPITCH + 4 + x;
                float s;
                if (kt == 0)
                    s = sB[base - 2*LPITCH] + sB[base - LPITCH] + sB[base]
                      + sB[base + LPITCH] + sB[base + 2*LPITCH];
                else if (kt == 1)
                    s = sA[base - 3*LPITCH] + sA[base - 2*LPITCH] + sA[base - LPITCH]
                      + sA[base] + sA[base + LPITCH] + sA[base + 2*LPITCH] + sA[base + 3*LPITCH];
                else
                    s = sB[base];
                float val = s * norm;
                vals[j] = val;
                vmin = fminf(vmin, val); vmax = fmaxf(vmax, val);
            }
        }
        #pragma unroll
        for (int m = 32; m >= 1; m >>= 1) {
            vmin = fminf(vmin, __shfl_xor(vmin, m, 64));
            vmax = fmaxf(vmax, __shfl_xor(vmax, m, 64));
        }
        if (lane == 0) { rmn[wv] = vmin; rmx[wv] = vmax; }
        __syncthreads();
        float mn = rmn[0], mx = rmx[0];
        #pragma unroll
        for (int ww = 1; ww < 16; ++ww) {
            mn = fminf(mn, rmn[ww]); mx = fmaxf(mx, rmx[ww]);
        }
        float inv = 1.f / (mx - mn + EPSF);
        #pragma unroll
        for (int j = 0; j < 4; ++j) {
            int q = tid + j * 1024;
            if (q < Ssz) {
                float nv = (vals[j] - mn) * inv;
                if (kt == 0) sF[q] = nv; else sF[q] += nv;
            }
        }
    }
    __syncthreads();

    // ---- corr final ----
    float wq3 = weight[b] * (1.f / 3.f);
    #pragma unroll
    for (int j = 0; j < 4; ++j) {
        int q = tid + j * 1024;
        if (q < Ssz) out[b * Ssz + q] = wq3 * sF[q];
    }
    #pragma unroll
    for (int j = 0; j < 2; ++j) {
        int o = tid + j * 1024;
        if (o >= 1189) continue;
        int O, p, outi;
        if (o < 900)       { O = 30; p = o;        outi = 7200 + b * 900 + p; }
        else if (o < 1125) { O = 15; p = o - 900;  outi = 9000 + b * 225 + p; }
        else               { O = 8;  p = o - 1125; outi = 9450 + b * 64 + p; }
        int y = p / O, x = p - y * O;
        float sc = 59.f / (float)(O - 1);
        float py = y * sc, px = x * sc;
        int y0 = (int)floorf(py), x0 = (int)floorf(px);
        int y1 = min(y0 + 1, 59), x1 = min(x0 + 1, 59);
        float wy = py - y0, wx = px - x0;
        float v = sF[y0 * 60 + x0] * (1.f - wy) * (1.f - wx)
                + sF[y1 * 60 + x0] * wy * (1.f - wx)
                + sF[y0 * 60 + x1] * (1.f - wy) * wx
                + sF[y1 * 60 + x1] * wy * wx;
        out[outi] = wq3 * v;
    }
}

extern "C" void kernel_launch(void* const* d_in, const int* in_sizes, int n_in,
                              void* d_out, int out_size, void* d_ws, size_t ws_size,
                              hipStream_t stream) {
    const float* weight = (const float*)d_in[0];
    const float* query  = (const float*)d_in[1];
    const float* supp   = (const float*)d_in[2];
    const float* masks  = (const float*)d_in[3];
    const float* kin    = (const float*)d_in[4];
    const float* text   = (const float*)d_in[5];
    const float* proto  = (const float*)d_in[6];
    const float* w_q    = (const float*)d_in[7];
    const float* w_k    = (const float*)d_in[8];
    const float* w_bl   = (const float*)d_in[9];
    const float* w_proj = (const float*)d_in[10];
    const float* b_proj = (const float*)d_in[11];
    float* out = (float*)d_out;
    float* ws  = (float*)d_ws;

    // zero atomic accumulator planes (SN2 + DOT)
    hipMemsetAsync(ws, 0, (size_t)OFF_WMAP * sizeof(float), stream);

    k_pool_u<<<1026, 256, 0, stream>>>(supp, masks, text, proto, w_q, w_bl, w_k, ws);
    k_wmap_score<<<82, 1024, 0, stream>>>(masks, kin, ws);
    k_v_kbar<<<1024, 256, 0, stream>>>(supp, kin, ws);
    k_dot_apa<<<482, 256, 0, stream>>>(query, w_k, w_proj, b_proj, proto, ws, out);
    k_simcorr<<<Bsz, 1024, 0, stream>>>(weight, ws, out);
}